// Round 11
// baseline (381.254 us; speedup 1.0000x reference)
//
#include <hip/hip_runtime.h>
#include <math.h>

// ---------------------------------------------------------------------------
// SheafGNN forward. R11:
//  - k_maps_expm v4: single-wave blocks (64 thr / 64 edges), LDS 8.6KB
//    stride-67 (2-way = free), __syncthreads == waitcnt only (no s_barrier
//    coupling); reads adjrow/adjcol linearly (CSR order) and writes MM
//    sequentially -- perm indirection eliminated.
//  - k_fill writes adjcol alongside adjrow.
//  - k_agg unroll-4 (four independent gather chains).
//  - Rest (MFMA GEMMs, 3-phase scan, packs) unchanged from R10.
// R10 post-mortem: maps was latency/occupancy-bound (Occ 31%, VALU 26%,
// halved loads didn't help); 2-wave blocks + 4 barriers coupled stalls.
// ---------------------------------------------------------------------------

using short8 = __attribute__((ext_vector_type(8))) short;
using f32x4 = __attribute__((ext_vector_type(4))) float;
typedef unsigned short u16;

__device__ __forceinline__ u16 f2bf(float f) {  // RNE fp32->bf16
  unsigned u = __float_as_uint(f);
  unsigned r = (u + 0x7FFFu + ((u >> 16) & 1u)) >> 16;
  return (u16)r;
}
__device__ __forceinline__ float bf2f(u16 v) {
  return __uint_as_float(((unsigned)v) << 16);
}

// ---- one-time packs (also zeroes cnt for the CSR histogram) ----------------
__global__ void __launch_bounds__(256) k_cvt_x(const float* __restrict__ x,
                                               u16* __restrict__ Xb,
                                               int* __restrict__ cnt, int n4,
                                               int N) {
  int i = blockIdx.x * 256 + threadIdx.x;
  if (i < N) cnt[i] = 0;
  if (i >= n4) return;
  float4 v = ((const float4*)x)[i];
  ushort4 o;
  o.x = f2bf(v.x);
  o.y = f2bf(v.y);
  o.z = f2bf(v.z);
  o.w = f2bf(v.w);
  ((ushort4*)Xb)[i] = o;
}

__global__ void __launch_bounds__(256) k_pack_w(const float* __restrict__ win,
    const float* __restrict__ w1a, const float* __restrict__ w1b,
    const float* __restrict__ wout, u16* __restrict__ WTin,
    u16* __restrict__ WT1a, u16* __restrict__ WT1b, u16* __restrict__ WTout) {
  int idx = blockIdx.x * 256 + threadIdx.x;
  if (idx < 16384) {
    int o = idx >> 7, i = idx & 127;
    WTin[idx] = f2bf(win[i * 128 + o]);
  } else if (idx < 32768) {
    int j = idx - 16384;
    int o = j >> 7, i = j & 127;
    WT1a[j] = f2bf(o < 64 ? w1a[i * 64 + o] : w1a[(128 + i) * 64 + (o - 64)]);
  } else if (idx < 49152) {
    int j = idx - 32768;
    int o = j >> 7, i = j & 127;
    WT1b[j] = f2bf(o < 64 ? w1b[i * 64 + o] : w1b[(128 + i) * 64 + (o - 64)]);
  } else if (idx < 57344) {
    int j = idx - 49152;
    int o = j >> 7, i = j & 127;  // o < 64
    WTout[j] = f2bf(wout[i * 64 + o]);
  }
}

// ---- bf16 MFMA GEMM: wave = one 16x16 tile, K=128 --------------------------
__global__ void __launch_bounds__(256) k_gemm_mfma(const u16* __restrict__ Ab,
    const u16* __restrict__ WT, const float* __restrict__ bias,
    float* __restrict__ C, u16* __restrict__ Cb, int N, int P) {
  int t = threadIdx.x;
  int wv = t >> 6, lane = t & 63;
  int row0 = (blockIdx.x << 6) + (wv << 4);
  int cb = blockIdx.y << 4;
  int col = lane & 15, quad = lane >> 4;
  const u16* wrow = WT + (size_t)(cb + col) * 128 + quad * 8;
  short8 b0 = *(const short8*)(wrow);
  short8 b1 = *(const short8*)(wrow + 32);
  short8 b2 = *(const short8*)(wrow + 64);
  short8 b3 = *(const short8*)(wrow + 96);
  float bv = bias ? bias[cb + col] : 0.f;
  const u16* ar = Ab + (size_t)(row0 + col) * 128 + quad * 8;
  short8 a0 = *(const short8*)(ar);
  short8 a1 = *(const short8*)(ar + 32);
  short8 a2 = *(const short8*)(ar + 64);
  short8 a3 = *(const short8*)(ar + 96);
  f32x4 acc = {0.f, 0.f, 0.f, 0.f};
  acc = __builtin_amdgcn_mfma_f32_16x16x32_bf16(a0, b0, acc, 0, 0, 0);
  acc = __builtin_amdgcn_mfma_f32_16x16x32_bf16(a1, b1, acc, 0, 0, 0);
  acc = __builtin_amdgcn_mfma_f32_16x16x32_bf16(a2, b2, acc, 0, 0, 0);
  acc = __builtin_amdgcn_mfma_f32_16x16x32_bf16(a3, b3, acc, 0, 0, 0);
#pragma unroll
  for (int r = 0; r < 4; ++r) {
    int row = row0 + quad * 4 + r;
    if (row < N) {
      float o = acc[r] + bv;
      if (C) C[(size_t)row * P + cb + col] = o;
      if (Cb) Cb[(size_t)row * 128 + cb + col] = f2bf(o);
    }
  }
}

// ---- CSR build (by col): hist -> 3-phase scan -> fill ----------------------
__global__ void __launch_bounds__(256) k_hist(const int* __restrict__ eidx,
                                              int* __restrict__ cnt, int E) {
  int e = blockIdx.x * 256 + threadIdx.x;
  if (e < E) atomicAdd(&cnt[eidx[E + e]], 1);
}

__global__ void __launch_bounds__(256) k_scanA(const int* __restrict__ cnt,
                                               int* __restrict__ bsum, int N) {
  __shared__ int sums[256];
  int b = blockIdx.x, t = threadIdx.x;
  int base = b * 2048 + t * 8;
  int s = 0;
#pragma unroll
  for (int k = 0; k < 8; ++k) {
    int i = base + k;
    if (i < N) s += cnt[i];
  }
  sums[t] = s;
  __syncthreads();
  for (int d = 128; d > 0; d >>= 1) {
    if (t < d) sums[t] += sums[t + d];
    __syncthreads();
  }
  if (t == 0) bsum[b] = sums[0];
}

__global__ void k_scanB(const int* __restrict__ bsum, int* __restrict__ boff,
                        int nb) {
  if (threadIdx.x == 0) {
    int run = 0;
    for (int b = 0; b < nb; ++b) {
      boff[b] = run;
      run += bsum[b];
    }
  }
}

__global__ void __launch_bounds__(256) k_scanC(const int* __restrict__ cnt,
    const int* __restrict__ boff, int* __restrict__ ptr,
    int* __restrict__ cursor, int N, int nblocks) {
  __shared__ int sums[256];
  int b = blockIdx.x, t = threadIdx.x;
  int base = b * 2048 + t * 8;
  int vals[8];
  int s = 0;
#pragma unroll
  for (int k = 0; k < 8; ++k) {
    int i = base + k;
    int c = (i < N) ? cnt[i] : 0;
    vals[k] = s;
    s += c;
  }
  sums[t] = s;
  __syncthreads();
  for (int d = 1; d < 256; d <<= 1) {
    int v = (t >= d) ? sums[t - d] : 0;
    __syncthreads();
    sums[t] += v;
    __syncthreads();
  }
  int toff = (t == 0) ? 0 : sums[t - 1];
  int bo = boff[b];
#pragma unroll
  for (int k = 0; k < 8; ++k) {
    int i = base + k;
    if (i < N) {
      int p = bo + toff + vals[k];
      ptr[i] = p;
      cursor[i] = p;
    }
  }
  if (b == nblocks - 1 && t == 255) ptr[N] = bo + sums[255];
}

// fill: CSR-slot scatter of (row, col) so downstream kernels read linearly.
__global__ void __launch_bounds__(256) k_fill(const int* __restrict__ eidx,
    int* __restrict__ cursor, int* __restrict__ adjrow,
    int* __restrict__ adjcol, int E) {
  int e = blockIdx.x * 256 + threadIdx.x;
  if (e >= E) return;
  int r = eidx[e], c = eidx[E + e];
  int pos = atomicAdd(&cursor[c], 1);
  adjrow[pos] = r;
  adjcol[pos] = c;
}

// ---- exact expm of antisym 4x4 via so(4) = su(2) + su(2) -------------------
__device__ __forceinline__ void so4_expm(const float* __restrict__ m,
                                         float* __restrict__ F) {
  float v1 = m[1] - m[4], v2 = m[2] - m[8], v3 = m[3] - m[12];
  float w1 = m[11] - m[14], w2 = m[13] - m[7], w3 = m[6] - m[9];
  float p1 = 0.5f * (v1 + w1), p2 = 0.5f * (v2 + w2), p3 = 0.5f * (v3 + w3);
  float q1 = 0.5f * (v1 - w1), q2 = 0.5f * (v2 - w2), q3 = 0.5f * (v3 - w3);
  float tp2 = p1 * p1 + p2 * p2 + p3 * p3;
  float tq2 = q1 * q1 + q2 * q2 + q3 * q3;
  float tp = sqrtf(tp2), tq = sqrtf(tq2);
  float cp = __cosf(tp);
  float sp = (tp > 1e-6f) ? (__sinf(tp) / tp) : (1.f - tp2 * (1.f / 6.f));
  float cq = __cosf(tq);
  float sq = (tq > 1e-6f) ? (__sinf(tq) / tq) : (1.f - tq2 * (1.f / 6.f));
  float a1 = sp * p1, a2 = sp * p2, a3 = sp * p3;
  float b1 = sq * q1, b2 = sq * q2, b3 = sq * q3;
  float Rp[16] = {cp,  a1,  a2,  a3,  -a1, cp,  a3,  -a2,
                  -a2, -a3, cp,  a1,  -a3, a2,  -a1, cp};
  float Rq[16] = {cq,  b1,  b2,  b3,  -b1, cq,  -b3, b2,
                  -b2, b3,  cq,  -b1, -b3, -b2, b1,  cq};
#pragma unroll
  for (int a = 0; a < 4; ++a)
#pragma unroll
    for (int b = 0; b < 4; ++b) {
      float s = 0.f;
#pragma unroll
      for (int c = 0; c < 4; ++c) s = fmaf(Rp[a * 4 + c], Rq[c * 4 + b], s);
      F[a * 4 + b] = s;
    }
}

// 64 edges / 64-thread (single-wave) block; edges in CSR order (adjrow/
// adjcol linear reads, MM sequential write). 2 K-chunks of 32 feats; LDS
// 32*67*4 = 8.6KB, stride 67 -> staged writes & reads 2-way (free).
// __syncthreads in a 1-wave block is just a waitcnt.
__global__ void __launch_bounds__(64) k_maps_expm(const u16* __restrict__ pqb,
    const float* __restrict__ w2, const float* __restrict__ b1,
    const float* __restrict__ b2, const int* __restrict__ adjrow,
    const int* __restrict__ adjcol, float* __restrict__ MM, int E) {
  __shared__ float Hst[32 * 67];  // [feat_local][edge]
  int t = threadIdx.x;
  int e0 = blockIdx.x * 64;
  int esub = t >> 2, c4 = t & 3;
  int rows[4], cols[4];
#pragma unroll
  for (int i = 0; i < 4; ++i) {
    int e = e0 + i * 16 + esub;
    int es = (e < E) ? e : (E - 1);
    rows[i] = adjrow[es];
    cols[i] = adjcol[es];
  }
  float acc[32];
#pragma unroll
  for (int o = 0; o < 32; ++o) acc[o] = b2[o];  // uniform -> s_load

  // ---- chunk 0: features 0..31 ----
#pragma unroll
  for (int i = 0; i < 4; ++i) {
    int eloc = i * 16 + esub;
    short8 pv = *(const short8*)(pqb + (size_t)rows[i] * 128 + c4 * 8);
    short8 qv = *(const short8*)(pqb + (size_t)cols[i] * 128 + 64 + c4 * 8);
#pragma unroll
    for (int k = 0; k < 8; ++k) {
      int f = c4 * 8 + k;
      float vv = bf2f((u16)pv[k]) + bf2f((u16)qv[k]) + b1[f];
      Hst[f * 67 + eloc] = fmaxf(vv, 0.f);
    }
  }
  __syncthreads();
  for (int m = 0; m < 32; ++m) {
    float hm = Hst[m * 67 + t];  // stride-1 across lanes
#pragma unroll
    for (int o = 0; o < 32; ++o)
      acc[o] = fmaf(hm, w2[m * 32 + o], acc[o]);  // s_load
  }
  __syncthreads();

  // ---- chunk 1: features 32..63 ----
#pragma unroll
  for (int i = 0; i < 4; ++i) {
    int eloc = i * 16 + esub;
    short8 pv = *(const short8*)(pqb + (size_t)rows[i] * 128 + 32 + c4 * 8);
    short8 qv = *(const short8*)(pqb + (size_t)cols[i] * 128 + 96 + c4 * 8);
#pragma unroll
    for (int k = 0; k < 8; ++k) {
      int f = c4 * 8 + k;
      float vv = bf2f((u16)pv[k]) + bf2f((u16)qv[k]) + b1[32 + f];
      Hst[f * 67 + eloc] = fmaxf(vv, 0.f);
    }
  }
  __syncthreads();
  for (int m = 0; m < 32; ++m) {
    float hm = Hst[m * 67 + t];
#pragma unroll
    for (int o = 0; o < 32; ++o)
      acc[o] = fmaf(hm, w2[(32 + m) * 32 + o], acc[o]);  // s_load
  }

  int e = e0 + t;
  if (e >= E) return;
  float Fu[16], Fv[16];
  so4_expm(acc, Fu);
  so4_expm(acc + 16, Fv);
  float out[32];
#pragma unroll
  for (int a = 0; a < 4; ++a)
#pragma unroll
    for (int b = 0; b < 4; ++b) {
      float s1 = 0.f, s2 = 0.f;
#pragma unroll
      for (int c = 0; c < 4; ++c) {
        s1 = fmaf(Fu[c * 4 + a], Fu[c * 4 + b], s1);  // (Fu^T Fu)[a,b]
        s2 = fmaf(Fu[c * 4 + a], Fv[c * 4 + b], s2);  // (Fu^T Fv)[a,b]
      }
      out[a * 4 + b] = s1;
      out[16 + a * 4 + b] = s2;
    }
  float* mp = MM + (size_t)e * 32;  // sequential (CSR order) -- no scatter
#pragma unroll
  for (int i = 0; i < 8; ++i) {
    float4 v = make_float4(out[i * 4], out[i * 4 + 1], out[i * 4 + 2],
                           out[i * 4 + 3]);
    *(float4*)(mp + i * 4) = v;
  }
}

// One wave per node: walk CSR segment (unroll-4: four independent gather
// chains), fused elu epilogue. Writes fp32 xout AND bf16 xoutb.
__global__ void __launch_bounds__(256) k_agg(const float* __restrict__ x,
    const float* __restrict__ MM, const int* __restrict__ ptr,
    const int* __restrict__ adjrow, const float* __restrict__ epsp,
    float* __restrict__ xout, u16* __restrict__ xoutb, int N) {
  int wv = threadIdx.x >> 6, lane = threadIdx.x & 63;
  int v = blockIdx.x * 4 + wv;
  if (v >= N) return;
  int p0 = ptr[v], p1 = ptr[v + 1];
  int a = lane & 3, kb = lane & ~3;
  const float* xv = x + (size_t)v * 128;
  float4 xi1 = *(const float4*)(xv + kb);
  float4 xi2 = *(const float4*)(xv + 64 + kb);
  float hv1 = xv[lane], hv2 = xv[64 + lane];
  float acc1 = 0.f, acc2 = 0.f;
  int j = p0;
  for (; j + 3 < p1; j += 4) {
#pragma unroll
    for (int u = 0; u < 4; ++u) {
      int r0 = adjrow[j + u];
      const float* mpa = MM + (size_t)(j + u) * 32;
      float4 am1 = *(const float4*)(mpa + a * 4);
      float4 am2 = *(const float4*)(mpa + 16 + a * 4);
      const float* xa = x + (size_t)r0 * 128;
      float4 xa1 = *(const float4*)(xa + kb);
      float4 xa2 = *(const float4*)(xa + 64 + kb);
      acc1 += am1.x * xi1.x + am1.y * xi1.y + am1.z * xi1.z + am1.w * xi1.w -
              (am2.x * xa1.x + am2.y * xa1.y + am2.z * xa1.z + am2.w * xa1.w);
      acc2 += am1.x * xi2.x + am1.y * xi2.y + am1.z * xi2.z + am1.w * xi2.w -
              (am2.x * xa2.x + am2.y * xa2.y + am2.z * xa2.z + am2.w * xa2.w);
    }
  }
  for (; j < p1; ++j) {
    int r0 = adjrow[j];
    const float* mpa = MM + (size_t)j * 32;
    float4 am1 = *(const float4*)(mpa + a * 4);
    float4 am2 = *(const float4*)(mpa + 16 + a * 4);
    const float* xa = x + (size_t)r0 * 128;
    float4 xa1 = *(const float4*)(xa + kb);
    float4 xa2 = *(const float4*)(xa + 64 + kb);
    acc1 += am1.x * xi1.x + am1.y * xi1.y + am1.z * xi1.z + am1.w * xi1.w -
            (am2.x * xa1.x + am2.y * xa1.y + am2.z * xa1.z + am2.w * xa1.w);
    acc2 += am1.x * xi2.x + am1.y * xi2.y + am1.z * xi2.z + am1.w * xi2.w -
            (am2.x * xa2.x + am2.y * xa2.y + am2.z * xa2.z + am2.w * xa2.w);
  }
  float eps = *epsp;
  float r1 = hv1 - eps * acc1;
  float r2 = hv2 - eps * acc2;
  r1 = (r1 > 0.f) ? r1 : expm1f(r1);
  r2 = (r2 > 0.f) ? r2 : expm1f(r2);
  xout[(size_t)v * 128 + lane] = r1;
  xout[(size_t)v * 128 + 64 + lane] = r2;
  xoutb[(size_t)v * 128 + lane] = f2bf(r1);
  xoutb[(size_t)v * 128 + 64 + lane] = f2bf(r2);
}

extern "C" void kernel_launch(void* const* d_in, const int* in_sizes, int n_in,
                              void* d_out, int out_size, void* d_ws,
                              size_t ws_size, hipStream_t stream) {
  const float* x = (const float*)d_in[0];
  const int* eidx = (const int*)d_in[1];
  const float* lin_in_w = (const float*)d_in[2];
  const float* lin_in_b = (const float*)d_in[3];
  const float* c0w1 = (const float*)d_in[4];
  const float* c0b1 = (const float*)d_in[5];
  const float* c0w2 = (const float*)d_in[6];
  const float* c0b2 = (const float*)d_in[7];
  const float* c0eps = (const float*)d_in[8];
  const float* c1w1 = (const float*)d_in[9];
  const float* c1b1 = (const float*)d_in[10];
  const float* c1w2 = (const float*)d_in[11];
  const float* c1b2 = (const float*)d_in[12];
  const float* c1eps = (const float*)d_in[13];
  const float* lout_w = (const float*)d_in[14];
  const float* lout_b = (const float*)d_in[15];
  float* out = (float*)d_out;

  int N = in_sizes[0] / 128;
  int E = in_sizes[1] / 2;
  int Npad = N + 64;

  char* ws = (char*)d_ws;
  size_t szH = (size_t)N * 128 * 4;
  size_t szHb = (size_t)Npad * 128 * 2;
  size_t szM = (size_t)E * 32 * 4;
  float* H = (float*)ws;
  float* H2 = (float*)(ws + szH);
  float* MAPS = (float*)(ws + 2 * szH);
  u16* Xb = (u16*)(ws + 2 * szH + szM);
  u16* Hb = (u16*)(ws + 2 * szH + szM + szHb);
  u16* H2b = (u16*)(ws + 2 * szH + szM + 2 * szHb);
  u16* PQb = (u16*)(ws + 2 * szH + szM + 3 * szHb);
  u16* WTin = (u16*)(ws + 2 * szH + szM + 4 * szHb);
  u16* WT1a = WTin + 16384;
  u16* WT1b = WT1a + 16384;
  u16* WTout = WT1b + 16384;
  char* ip = (char*)(WTout + 8192);
  int* cnt = (int*)ip;                                   // N
  int* ptr = (int*)(ip + 4 * (size_t)(N + 64));          // N+1
  int* cursor = (int*)(ip + 8 * (size_t)(N + 64));       // N
  int* adjrow = (int*)(ip + 12 * (size_t)(N + 64));      // E
  int* adjcol = (int*)(ip + 12 * (size_t)(N + 64) + 4 * (size_t)E);  // E
  int* bsum = adjcol + E;                                // 64
  int* boff = bsum + 64;                                 // 64

  dim3 blk(256);
  int gN = (N + 63) / 64;
  int gE = (E + 255) / 256;
  int nsb = (N + 2047) / 2048;

  // packs (+cnt zero), CSR build
  k_cvt_x<<<(N * 32 + 255) / 256, blk, 0, stream>>>(x, Xb, cnt, N * 32, N);
  k_pack_w<<<224, blk, 0, stream>>>(lin_in_w, c0w1, c1w1, lout_w, WTin, WT1a,
                                    WT1b, WTout);
  k_hist<<<gE, blk, 0, stream>>>(eidx, cnt, E);
  k_scanA<<<nsb, blk, 0, stream>>>(cnt, bsum, N);
  k_scanB<<<1, dim3(64), 0, stream>>>(bsum, boff, nsb);
  k_scanC<<<nsb, blk, 0, stream>>>(cnt, boff, ptr, cursor, N, nsb);
  k_fill<<<gE, blk, 0, stream>>>(eidx, cursor, adjrow, adjcol, E);

  // h0 = x @ lin_in_w + b   (fp32 H + bf16 Hb)
  k_gemm_mfma<<<dim3(gN, 8), blk, 0, stream>>>(Xb, WTin, lin_in_b, H, Hb, N,
                                               128);

  float* cur = H;
  float* nxt = H2;
  u16* curb = Hb;
  u16* nxtb = H2b;
  for (int layer = 0; layer < 2; ++layer) {
    const u16* wt1 = layer ? WT1b : WT1a;
    const float* b1 = layer ? c1b1 : c0b1;
    const float* w2 = layer ? c1w2 : c0w2;
    const float* b2 = layer ? c1b2 : c0b2;
    const float* ep = layer ? c1eps : c0eps;
    k_gemm_mfma<<<dim3(gN, 8), blk, 0, stream>>>(curb, wt1, nullptr, nullptr,
                                                 PQb, N, 128);
    k_maps_expm<<<(E + 63) / 64, dim3(64), 0, stream>>>(PQb, w2, b1, b2,
                                                        adjrow, adjcol, MAPS,
                                                        E);
    k_agg<<<(N + 3) / 4, blk, 0, stream>>>(cur, MAPS, ptr, adjrow, ep, nxt,
                                           nxtb, N);
    float* tf = cur; cur = nxt; nxt = tf;
    u16* tb = curb; curb = nxtb; nxtb = tb;
  }

  // out = h @ lin_out_w + b
  k_gemm_mfma<<<dim3(gN, 4), blk, 0, stream>>>(curb, WTout, lout_b, out,
                                               nullptr, N, 64);
}

// Round 12
// 329.700 us; speedup vs baseline: 1.1564x; 1.1564x over previous
//
#include <hip/hip_runtime.h>
#include <math.h>

// ---------------------------------------------------------------------------
// SheafGNN forward. R12:
//  - k_agg v4: unroll-2 (R11's unroll-4 regressed 52->58: +12 VGPR, no occ
//    gain); self-term factored exactly: sum(M1_e . x_i) = (sum M1_e) . x_i;
//    M read as bf16 interleaved [M1row|M2row] (1x16B broadcast/edge/lane);
//    x_r gathered from the bf16 feature array (8B loads) -> gather bytes /2.
//  - k_maps_expm: writes MM as bf16 pair layout (write traffic 41->20MB).
//  - Rest unchanged from R11 (MFMA GEMMs, 3-phase scan, single-wave maps).
// ---------------------------------------------------------------------------

using short8 = __attribute__((ext_vector_type(8))) short;
using f32x4 = __attribute__((ext_vector_type(4))) float;
typedef unsigned short u16;

__device__ __forceinline__ u16 f2bf(float f) {  // RNE fp32->bf16
  unsigned u = __float_as_uint(f);
  unsigned r = (u + 0x7FFFu + ((u >> 16) & 1u)) >> 16;
  return (u16)r;
}
__device__ __forceinline__ float bf2f(u16 v) {
  return __uint_as_float(((unsigned)v) << 16);
}

// ---- one-time packs (also zeroes cnt for the CSR histogram) ----------------
__global__ void __launch_bounds__(256) k_cvt_x(const float* __restrict__ x,
                                               u16* __restrict__ Xb,
                                               int* __restrict__ cnt, int n4,
                                               int N) {
  int i = blockIdx.x * 256 + threadIdx.x;
  if (i < N) cnt[i] = 0;
  if (i >= n4) return;
  float4 v = ((const float4*)x)[i];
  ushort4 o;
  o.x = f2bf(v.x);
  o.y = f2bf(v.y);
  o.z = f2bf(v.z);
  o.w = f2bf(v.w);
  ((ushort4*)Xb)[i] = o;
}

__global__ void __launch_bounds__(256) k_pack_w(const float* __restrict__ win,
    const float* __restrict__ w1a, const float* __restrict__ w1b,
    const float* __restrict__ wout, u16* __restrict__ WTin,
    u16* __restrict__ WT1a, u16* __restrict__ WT1b, u16* __restrict__ WTout) {
  int idx = blockIdx.x * 256 + threadIdx.x;
  if (idx < 16384) {
    int o = idx >> 7, i = idx & 127;
    WTin[idx] = f2bf(win[i * 128 + o]);
  } else if (idx < 32768) {
    int j = idx - 16384;
    int o = j >> 7, i = j & 127;
    WT1a[j] = f2bf(o < 64 ? w1a[i * 64 + o] : w1a[(128 + i) * 64 + (o - 64)]);
  } else if (idx < 49152) {
    int j = idx - 32768;
    int o = j >> 7, i = j & 127;
    WT1b[j] = f2bf(o < 64 ? w1b[i * 64 + o] : w1b[(128 + i) * 64 + (o - 64)]);
  } else if (idx < 57344) {
    int j = idx - 49152;
    int o = j >> 7, i = j & 127;  // o < 64
    WTout[j] = f2bf(wout[i * 64 + o]);
  }
}

// ---- bf16 MFMA GEMM: wave = one 16x16 tile, K=128 --------------------------
__global__ void __launch_bounds__(256) k_gemm_mfma(const u16* __restrict__ Ab,
    const u16* __restrict__ WT, const float* __restrict__ bias,
    float* __restrict__ C, u16* __restrict__ Cb, int N, int P) {
  int t = threadIdx.x;
  int wv = t >> 6, lane = t & 63;
  int row0 = (blockIdx.x << 6) + (wv << 4);
  int cb = blockIdx.y << 4;
  int col = lane & 15, quad = lane >> 4;
  const u16* wrow = WT + (size_t)(cb + col) * 128 + quad * 8;
  short8 b0 = *(const short8*)(wrow);
  short8 b1 = *(const short8*)(wrow + 32);
  short8 b2 = *(const short8*)(wrow + 64);
  short8 b3 = *(const short8*)(wrow + 96);
  float bv = bias ? bias[cb + col] : 0.f;
  const u16* ar = Ab + (size_t)(row0 + col) * 128 + quad * 8;
  short8 a0 = *(const short8*)(ar);
  short8 a1 = *(const short8*)(ar + 32);
  short8 a2 = *(const short8*)(ar + 64);
  short8 a3 = *(const short8*)(ar + 96);
  f32x4 acc = {0.f, 0.f, 0.f, 0.f};
  acc = __builtin_amdgcn_mfma_f32_16x16x32_bf16(a0, b0, acc, 0, 0, 0);
  acc = __builtin_amdgcn_mfma_f32_16x16x32_bf16(a1, b1, acc, 0, 0, 0);
  acc = __builtin_amdgcn_mfma_f32_16x16x32_bf16(a2, b2, acc, 0, 0, 0);
  acc = __builtin_amdgcn_mfma_f32_16x16x32_bf16(a3, b3, acc, 0, 0, 0);
#pragma unroll
  for (int r = 0; r < 4; ++r) {
    int row = row0 + quad * 4 + r;
    if (row < N) {
      float o = acc[r] + bv;
      if (C) C[(size_t)row * P + cb + col] = o;
      if (Cb) Cb[(size_t)row * 128 + cb + col] = f2bf(o);
    }
  }
}

// ---- CSR build (by col): hist -> 3-phase scan -> fill ----------------------
__global__ void __launch_bounds__(256) k_hist(const int* __restrict__ eidx,
                                              int* __restrict__ cnt, int E) {
  int e = blockIdx.x * 256 + threadIdx.x;
  if (e < E) atomicAdd(&cnt[eidx[E + e]], 1);
}

__global__ void __launch_bounds__(256) k_scanA(const int* __restrict__ cnt,
                                               int* __restrict__ bsum, int N) {
  __shared__ int sums[256];
  int b = blockIdx.x, t = threadIdx.x;
  int base = b * 2048 + t * 8;
  int s = 0;
#pragma unroll
  for (int k = 0; k < 8; ++k) {
    int i = base + k;
    if (i < N) s += cnt[i];
  }
  sums[t] = s;
  __syncthreads();
  for (int d = 128; d > 0; d >>= 1) {
    if (t < d) sums[t] += sums[t + d];
    __syncthreads();
  }
  if (t == 0) bsum[b] = sums[0];
}

__global__ void k_scanB(const int* __restrict__ bsum, int* __restrict__ boff,
                        int nb) {
  if (threadIdx.x == 0) {
    int run = 0;
    for (int b = 0; b < nb; ++b) {
      boff[b] = run;
      run += bsum[b];
    }
  }
}

__global__ void __launch_bounds__(256) k_scanC(const int* __restrict__ cnt,
    const int* __restrict__ boff, int* __restrict__ ptr,
    int* __restrict__ cursor, int N, int nblocks) {
  __shared__ int sums[256];
  int b = blockIdx.x, t = threadIdx.x;
  int base = b * 2048 + t * 8;
  int vals[8];
  int s = 0;
#pragma unroll
  for (int k = 0; k < 8; ++k) {
    int i = base + k;
    int c = (i < N) ? cnt[i] : 0;
    vals[k] = s;
    s += c;
  }
  sums[t] = s;
  __syncthreads();
  for (int d = 1; d < 256; d <<= 1) {
    int v = (t >= d) ? sums[t - d] : 0;
    __syncthreads();
    sums[t] += v;
    __syncthreads();
  }
  int toff = (t == 0) ? 0 : sums[t - 1];
  int bo = boff[b];
#pragma unroll
  for (int k = 0; k < 8; ++k) {
    int i = base + k;
    if (i < N) {
      int p = bo + toff + vals[k];
      ptr[i] = p;
      cursor[i] = p;
    }
  }
  if (b == nblocks - 1 && t == 255) ptr[N] = bo + sums[255];
}

// fill: CSR-slot scatter of (row, col) so downstream kernels read linearly.
__global__ void __launch_bounds__(256) k_fill(const int* __restrict__ eidx,
    int* __restrict__ cursor, int* __restrict__ adjrow,
    int* __restrict__ adjcol, int E) {
  int e = blockIdx.x * 256 + threadIdx.x;
  if (e >= E) return;
  int r = eidx[e], c = eidx[E + e];
  int pos = atomicAdd(&cursor[c], 1);
  adjrow[pos] = r;
  adjcol[pos] = c;
}

// ---- exact expm of antisym 4x4 via so(4) = su(2) + su(2) -------------------
__device__ __forceinline__ void so4_expm(const float* __restrict__ m,
                                         float* __restrict__ F) {
  float v1 = m[1] - m[4], v2 = m[2] - m[8], v3 = m[3] - m[12];
  float w1 = m[11] - m[14], w2 = m[13] - m[7], w3 = m[6] - m[9];
  float p1 = 0.5f * (v1 + w1), p2 = 0.5f * (v2 + w2), p3 = 0.5f * (v3 + w3);
  float q1 = 0.5f * (v1 - w1), q2 = 0.5f * (v2 - w2), q3 = 0.5f * (v3 - w3);
  float tp2 = p1 * p1 + p2 * p2 + p3 * p3;
  float tq2 = q1 * q1 + q2 * q2 + q3 * q3;
  float tp = sqrtf(tp2), tq = sqrtf(tq2);
  float cp = __cosf(tp);
  float sp = (tp > 1e-6f) ? (__sinf(tp) / tp) : (1.f - tp2 * (1.f / 6.f));
  float cq = __cosf(tq);
  float sq = (tq > 1e-6f) ? (__sinf(tq) / tq) : (1.f - tq2 * (1.f / 6.f));
  float a1 = sp * p1, a2 = sp * p2, a3 = sp * p3;
  float b1 = sq * q1, b2 = sq * q2, b3 = sq * q3;
  float Rp[16] = {cp,  a1,  a2,  a3,  -a1, cp,  a3,  -a2,
                  -a2, -a3, cp,  a1,  -a3, a2,  -a1, cp};
  float Rq[16] = {cq,  b1,  b2,  b3,  -b1, cq,  -b3, b2,
                  -b2, b3,  cq,  -b1, -b3, -b2, b1,  cq};
#pragma unroll
  for (int a = 0; a < 4; ++a)
#pragma unroll
    for (int b = 0; b < 4; ++b) {
      float s = 0.f;
#pragma unroll
      for (int c = 0; c < 4; ++c) s = fmaf(Rp[a * 4 + c], Rq[c * 4 + b], s);
      F[a * 4 + b] = s;
    }
}

// 64 edges / single-wave block; CSR-order linear reads, sequential MM write.
// Output: bf16, interleaved per a-row: [M1[a][0..3] | M2[a][0..3]] x 4.
__global__ void __launch_bounds__(64) k_maps_expm(const u16* __restrict__ pqb,
    const float* __restrict__ w2, const float* __restrict__ b1,
    const float* __restrict__ b2, const int* __restrict__ adjrow,
    const int* __restrict__ adjcol, u16* __restrict__ MMb, int E) {
  __shared__ float Hst[32 * 67];  // [feat_local][edge]
  int t = threadIdx.x;
  int e0 = blockIdx.x * 64;
  int esub = t >> 2, c4 = t & 3;
  int rows[4], cols[4];
#pragma unroll
  for (int i = 0; i < 4; ++i) {
    int e = e0 + i * 16 + esub;
    int es = (e < E) ? e : (E - 1);
    rows[i] = adjrow[es];
    cols[i] = adjcol[es];
  }
  float acc[32];
#pragma unroll
  for (int o = 0; o < 32; ++o) acc[o] = b2[o];  // uniform -> s_load

  // ---- chunk 0: features 0..31 ----
#pragma unroll
  for (int i = 0; i < 4; ++i) {
    int eloc = i * 16 + esub;
    short8 pv = *(const short8*)(pqb + (size_t)rows[i] * 128 + c4 * 8);
    short8 qv = *(const short8*)(pqb + (size_t)cols[i] * 128 + 64 + c4 * 8);
#pragma unroll
    for (int k = 0; k < 8; ++k) {
      int f = c4 * 8 + k;
      float vv = bf2f((u16)pv[k]) + bf2f((u16)qv[k]) + b1[f];
      Hst[f * 67 + eloc] = fmaxf(vv, 0.f);
    }
  }
  __syncthreads();
  for (int m = 0; m < 32; ++m) {
    float hm = Hst[m * 67 + t];  // stride-1 across lanes
#pragma unroll
    for (int o = 0; o < 32; ++o)
      acc[o] = fmaf(hm, w2[m * 32 + o], acc[o]);  // s_load
  }
  __syncthreads();

  // ---- chunk 1: features 32..63 ----
#pragma unroll
  for (int i = 0; i < 4; ++i) {
    int eloc = i * 16 + esub;
    short8 pv = *(const short8*)(pqb + (size_t)rows[i] * 128 + 32 + c4 * 8);
    short8 qv = *(const short8*)(pqb + (size_t)cols[i] * 128 + 96 + c4 * 8);
#pragma unroll
    for (int k = 0; k < 8; ++k) {
      int f = c4 * 8 + k;
      float vv = bf2f((u16)pv[k]) + bf2f((u16)qv[k]) + b1[32 + f];
      Hst[f * 67 + eloc] = fmaxf(vv, 0.f);
    }
  }
  __syncthreads();
  for (int m = 0; m < 32; ++m) {
    float hm = Hst[m * 67 + t];
#pragma unroll
    for (int o = 0; o < 32; ++o)
      acc[o] = fmaf(hm, w2[(32 + m) * 32 + o], acc[o]);  // s_load
  }

  int e = e0 + t;
  if (e >= E) return;
  float Fu[16], Fv[16];
  so4_expm(acc, Fu);
  so4_expm(acc + 16, Fv);
  u16 ob[32];
#pragma unroll
  for (int a = 0; a < 4; ++a)
#pragma unroll
    for (int b = 0; b < 4; ++b) {
      float s1 = 0.f, s2 = 0.f;
#pragma unroll
      for (int c = 0; c < 4; ++c) {
        s1 = fmaf(Fu[c * 4 + a], Fu[c * 4 + b], s1);  // (Fu^T Fu)[a,b]
        s2 = fmaf(Fu[c * 4 + a], Fv[c * 4 + b], s2);  // (Fu^T Fv)[a,b]
      }
      ob[a * 8 + b] = f2bf(s1);
      ob[a * 8 + 4 + b] = f2bf(s2);
    }
  u16* mp = MMb + (size_t)e * 32;  // sequential (CSR order), 64B/edge
#pragma unroll
  for (int i = 0; i < 4; ++i) *(short8*)(mp + i * 8) = *(short8*)(ob + i * 8);
}

// One wave per node: walk CSR segment (unroll-2). Self-term factored:
// sum_e(M1_e . x_i) = (sum_e M1_e) . x_i. M read bf16 (1x16B/edge/lane),
// x_r gathered bf16 (2x8B). Fused elu epilogue; emits fp32 + bf16.
__global__ void __launch_bounds__(256) k_agg(const float* __restrict__ x,
    const u16* __restrict__ xgb, const u16* __restrict__ MMb,
    const int* __restrict__ ptr, const int* __restrict__ adjrow,
    const float* __restrict__ epsp, float* __restrict__ xout,
    u16* __restrict__ xoutb, int N) {
  int wv = threadIdx.x >> 6, lane = threadIdx.x & 63;
  int v = blockIdx.x * 4 + wv;
  if (v >= N) return;
  int p0 = ptr[v], p1 = ptr[v + 1];
  int a = lane & 3, kb = lane & ~3;
  const float* xv = x + (size_t)v * 128;
  float4 xi1 = *(const float4*)(xv + kb);
  float4 xi2 = *(const float4*)(xv + 64 + kb);
  float hv1 = xv[lane], hv2 = xv[64 + lane];
  float s10 = 0.f, s11 = 0.f, s12 = 0.f, s13 = 0.f;  // sum of M1 row a
  float acc1 = 0.f, acc2 = 0.f;                       // -sum M2.x_r
  int j = p0;
  for (; j + 1 < p1; j += 2) {
    int r0 = adjrow[j], r1 = adjrow[j + 1];
    short8 ma = *(const short8*)(MMb + (size_t)j * 32 + a * 8);
    short8 mb = *(const short8*)(MMb + (size_t)(j + 1) * 32 + a * 8);
    ushort4 ya1 = *(const ushort4*)(xgb + (size_t)r0 * 128 + kb);
    ushort4 ya2 = *(const ushort4*)(xgb + (size_t)r0 * 128 + 64 + kb);
    ushort4 yb1 = *(const ushort4*)(xgb + (size_t)r1 * 128 + kb);
    ushort4 yb2 = *(const ushort4*)(xgb + (size_t)r1 * 128 + 64 + kb);
    s10 += bf2f((u16)ma[0]) + bf2f((u16)mb[0]);
    s11 += bf2f((u16)ma[1]) + bf2f((u16)mb[1]);
    s12 += bf2f((u16)ma[2]) + bf2f((u16)mb[2]);
    s13 += bf2f((u16)ma[3]) + bf2f((u16)mb[3]);
    float a4 = bf2f((u16)ma[4]), a5 = bf2f((u16)ma[5]);
    float a6 = bf2f((u16)ma[6]), a7 = bf2f((u16)ma[7]);
    float b4 = bf2f((u16)mb[4]), b5 = bf2f((u16)mb[5]);
    float b6 = bf2f((u16)mb[6]), b7 = bf2f((u16)mb[7]);
    acc1 -= a4 * bf2f(ya1.x) + a5 * bf2f(ya1.y) + a6 * bf2f(ya1.z) +
            a7 * bf2f(ya1.w);
    acc2 -= a4 * bf2f(ya2.x) + a5 * bf2f(ya2.y) + a6 * bf2f(ya2.z) +
            a7 * bf2f(ya2.w);
    acc1 -= b4 * bf2f(yb1.x) + b5 * bf2f(yb1.y) + b6 * bf2f(yb1.z) +
            b7 * bf2f(yb1.w);
    acc2 -= b4 * bf2f(yb2.x) + b5 * bf2f(yb2.y) + b6 * bf2f(yb2.z) +
            b7 * bf2f(yb2.w);
  }
  if (j < p1) {
    int r0 = adjrow[j];
    short8 ma = *(const short8*)(MMb + (size_t)j * 32 + a * 8);
    ushort4 ya1 = *(const ushort4*)(xgb + (size_t)r0 * 128 + kb);
    ushort4 ya2 = *(const ushort4*)(xgb + (size_t)r0 * 128 + 64 + kb);
    s10 += bf2f((u16)ma[0]);
    s11 += bf2f((u16)ma[1]);
    s12 += bf2f((u16)ma[2]);
    s13 += bf2f((u16)ma[3]);
    float a4 = bf2f((u16)ma[4]), a5 = bf2f((u16)ma[5]);
    float a6 = bf2f((u16)ma[6]), a7 = bf2f((u16)ma[7]);
    acc1 -= a4 * bf2f(ya1.x) + a5 * bf2f(ya1.y) + a6 * bf2f(ya1.z) +
            a7 * bf2f(ya1.w);
    acc2 -= a4 * bf2f(ya2.x) + a5 * bf2f(ya2.y) + a6 * bf2f(ya2.z) +
            a7 * bf2f(ya2.w);
  }
  acc1 += s10 * xi1.x + s11 * xi1.y + s12 * xi1.z + s13 * xi1.w;
  acc2 += s10 * xi2.x + s11 * xi2.y + s12 * xi2.z + s13 * xi2.w;
  float eps = *epsp;
  float r1 = hv1 - eps * acc1;
  float r2 = hv2 - eps * acc2;
  r1 = (r1 > 0.f) ? r1 : expm1f(r1);
  r2 = (r2 > 0.f) ? r2 : expm1f(r2);
  xout[(size_t)v * 128 + lane] = r1;
  xout[(size_t)v * 128 + 64 + lane] = r2;
  xoutb[(size_t)v * 128 + lane] = f2bf(r1);
  xoutb[(size_t)v * 128 + 64 + lane] = f2bf(r2);
}

extern "C" void kernel_launch(void* const* d_in, const int* in_sizes, int n_in,
                              void* d_out, int out_size, void* d_ws,
                              size_t ws_size, hipStream_t stream) {
  const float* x = (const float*)d_in[0];
  const int* eidx = (const int*)d_in[1];
  const float* lin_in_w = (const float*)d_in[2];
  const float* lin_in_b = (const float*)d_in[3];
  const float* c0w1 = (const float*)d_in[4];
  const float* c0b1 = (const float*)d_in[5];
  const float* c0w2 = (const float*)d_in[6];
  const float* c0b2 = (const float*)d_in[7];
  const float* c0eps = (const float*)d_in[8];
  const float* c1w1 = (const float*)d_in[9];
  const float* c1b1 = (const float*)d_in[10];
  const float* c1w2 = (const float*)d_in[11];
  const float* c1b2 = (const float*)d_in[12];
  const float* c1eps = (const float*)d_in[13];
  const float* lout_w = (const float*)d_in[14];
  const float* lout_b = (const float*)d_in[15];
  float* out = (float*)d_out;

  int N = in_sizes[0] / 128;
  int E = in_sizes[1] / 2;
  int Npad = N + 64;

  char* ws = (char*)d_ws;
  size_t szH = (size_t)N * 128 * 4;
  size_t szHb = (size_t)Npad * 128 * 2;
  size_t szM = (size_t)E * 32 * 2;  // bf16 MM
  float* H = (float*)ws;
  float* H2 = (float*)(ws + szH);
  u16* MMb = (u16*)(ws + 2 * szH);
  u16* Xb = (u16*)(ws + 2 * szH + szM);
  u16* Hb = (u16*)(ws + 2 * szH + szM + szHb);
  u16* H2b = (u16*)(ws + 2 * szH + szM + 2 * szHb);
  u16* PQb = (u16*)(ws + 2 * szH + szM + 3 * szHb);
  u16* WTin = (u16*)(ws + 2 * szH + szM + 4 * szHb);
  u16* WT1a = WTin + 16384;
  u16* WT1b = WT1a + 16384;
  u16* WTout = WT1b + 16384;
  char* ip = (char*)(WTout + 8192);
  int* cnt = (int*)ip;                                   // N
  int* ptr = (int*)(ip + 4 * (size_t)(N + 64));          // N+1
  int* cursor = (int*)(ip + 8 * (size_t)(N + 64));       // N
  int* adjrow = (int*)(ip + 12 * (size_t)(N + 64));      // E
  int* adjcol = (int*)(ip + 12 * (size_t)(N + 64) + 4 * (size_t)E);  // E
  int* bsum = adjcol + E;                                // 64
  int* boff = bsum + 64;                                 // 64

  dim3 blk(256);
  int gN = (N + 63) / 64;
  int gE = (E + 255) / 256;
  int nsb = (N + 2047) / 2048;

  // packs (+cnt zero), CSR build
  k_cvt_x<<<(N * 32 + 255) / 256, blk, 0, stream>>>(x, Xb, cnt, N * 32, N);
  k_pack_w<<<224, blk, 0, stream>>>(lin_in_w, c0w1, c1w1, lout_w, WTin, WT1a,
                                    WT1b, WTout);
  k_hist<<<gE, blk, 0, stream>>>(eidx, cnt, E);
  k_scanA<<<nsb, blk, 0, stream>>>(cnt, bsum, N);
  k_scanB<<<1, dim3(64), 0, stream>>>(bsum, boff, nsb);
  k_scanC<<<nsb, blk, 0, stream>>>(cnt, boff, ptr, cursor, N, nsb);
  k_fill<<<gE, blk, 0, stream>>>(eidx, cursor, adjrow, adjcol, E);

  // h0 = x @ lin_in_w + b   (fp32 H + bf16 Hb)
  k_gemm_mfma<<<dim3(gN, 8), blk, 0, stream>>>(Xb, WTin, lin_in_b, H, Hb, N,
                                               128);

  float* cur = H;
  float* nxt = H2;
  u16* curb = Hb;
  u16* nxtb = H2b;
  for (int layer = 0; layer < 2; ++layer) {
    const u16* wt1 = layer ? WT1b : WT1a;
    const float* b1 = layer ? c1b1 : c0b1;
    const float* w2 = layer ? c1w2 : c0w2;
    const float* b2 = layer ? c1b2 : c0b2;
    const float* ep = layer ? c1eps : c0eps;
    k_gemm_mfma<<<dim3(gN, 8), blk, 0, stream>>>(curb, wt1, nullptr, nullptr,
                                                 PQb, N, 128);
    k_maps_expm<<<(E + 63) / 64, dim3(64), 0, stream>>>(PQb, w2, b1, b2,
                                                        adjrow, adjcol, MMb,
                                                        E);
    k_agg<<<(N + 3) / 4, blk, 0, stream>>>(cur, curb, MMb, ptr, adjrow, ep,
                                           nxt, nxtb, N);
    float* tf = cur; cur = nxt; nxt = tf;
    u16* tb = curb; curb = nxtb; nxtb = tb;
  }

  // out = h @ lin_out_w + b
  k_gemm_mfma<<<dim3(gN, 4), blk, 0, stream>>>(curb, WTout, lout_b, out,
                                               nullptr, N, 64);
}

// Round 13
// 320.106 us; speedup vs baseline: 1.1910x; 1.0300x over previous
//
#include <hip/hip_runtime.h>
#include <math.h>

// ---------------------------------------------------------------------------
// SheafGNN forward. R13:
//  - k_maps_expm v6: h@w2 on MFMA. Wave = 16 edges: gather p/q bf16 ->
//    A-frag [m=edge][k=feat]; B-frags = w2^T bf16 (new pack); 4 MFMAs
//    replace 2048 scalar FMAs/edge. C (col=output,row=edge) -> per-wave
//    16x36 LDS patch (same-wave, no cross-wave dep) -> lanes 0..15 do
//    closed-form so(4) expm + M-products + bf16 interleaved store.
//    Wave count 4x (20000), VALU/wave ~4x down -> attacks the 73% stall.
//  - Everything else unchanged from R12 (MFMA GEMMs, 3-phase scan,
//    factored bf16 agg).
// R12 post-mortem: maps stuck ~53us across 3 memory-side fixes (VALU 26%,
// Occ 28%) -> the scalar 64x32 GEMM per edge-thread was the structure.
// ---------------------------------------------------------------------------

using short8 = __attribute__((ext_vector_type(8))) short;
using f32x4 = __attribute__((ext_vector_type(4))) float;
typedef unsigned short u16;

__device__ __forceinline__ u16 f2bf(float f) {  // RNE fp32->bf16
  unsigned u = __float_as_uint(f);
  unsigned r = (u + 0x7FFFu + ((u >> 16) & 1u)) >> 16;
  return (u16)r;
}
__device__ __forceinline__ float bf2f(u16 v) {
  return __uint_as_float(((unsigned)v) << 16);
}

// ---- one-time packs (also zeroes cnt for the CSR histogram) ----------------
__global__ void __launch_bounds__(256) k_cvt_x(const float* __restrict__ x,
                                               u16* __restrict__ Xb,
                                               int* __restrict__ cnt, int n4,
                                               int N) {
  int i = blockIdx.x * 256 + threadIdx.x;
  if (i < N) cnt[i] = 0;
  if (i >= n4) return;
  float4 v = ((const float4*)x)[i];
  ushort4 o;
  o.x = f2bf(v.x);
  o.y = f2bf(v.y);
  o.z = f2bf(v.z);
  o.w = f2bf(v.w);
  ((ushort4*)Xb)[i] = o;
}

// Weight packs: W^T bf16 for the node GEMMs, plus w2^T bf16 for maps-MFMA.
__global__ void __launch_bounds__(256) k_pack_w(const float* __restrict__ win,
    const float* __restrict__ w1a, const float* __restrict__ w1b,
    const float* __restrict__ wout, const float* __restrict__ w2a,
    const float* __restrict__ w2b, u16* __restrict__ WTin,
    u16* __restrict__ WT1a, u16* __restrict__ WT1b, u16* __restrict__ WTout,
    u16* __restrict__ W2Ta, u16* __restrict__ W2Tb) {
  int idx = blockIdx.x * 256 + threadIdx.x;
  if (idx < 16384) {
    int o = idx >> 7, i = idx & 127;
    WTin[idx] = f2bf(win[i * 128 + o]);
  } else if (idx < 32768) {
    int j = idx - 16384;
    int o = j >> 7, i = j & 127;
    WT1a[j] = f2bf(o < 64 ? w1a[i * 64 + o] : w1a[(128 + i) * 64 + (o - 64)]);
  } else if (idx < 49152) {
    int j = idx - 32768;
    int o = j >> 7, i = j & 127;
    WT1b[j] = f2bf(o < 64 ? w1b[i * 64 + o] : w1b[(128 + i) * 64 + (o - 64)]);
  } else if (idx < 57344) {
    int j = idx - 49152;
    int o = j >> 7, i = j & 127;  // o < 64
    WTout[j] = f2bf(wout[i * 64 + o]);
  } else if (idx < 59392) {
    int j = idx - 57344;
    int o = j >> 6, k = j & 63;  // W2T[o][k] = w2[k][o]
    W2Ta[j] = f2bf(w2a[k * 32 + o]);
  } else if (idx < 61440) {
    int j = idx - 59392;
    int o = j >> 6, k = j & 63;
    W2Tb[j] = f2bf(w2b[k * 32 + o]);
  }
}

// ---- bf16 MFMA GEMM: wave = one 16x16 tile, K=128 --------------------------
__global__ void __launch_bounds__(256) k_gemm_mfma(const u16* __restrict__ Ab,
    const u16* __restrict__ WT, const float* __restrict__ bias,
    float* __restrict__ C, u16* __restrict__ Cb, int N, int P) {
  int t = threadIdx.x;
  int wv = t >> 6, lane = t & 63;
  int row0 = (blockIdx.x << 6) + (wv << 4);
  int cb = blockIdx.y << 4;
  int col = lane & 15, quad = lane >> 4;
  const u16* wrow = WT + (size_t)(cb + col) * 128 + quad * 8;
  short8 b0 = *(const short8*)(wrow);
  short8 b1 = *(const short8*)(wrow + 32);
  short8 b2 = *(const short8*)(wrow + 64);
  short8 b3 = *(const short8*)(wrow + 96);
  float bv = bias ? bias[cb + col] : 0.f;
  const u16* ar = Ab + (size_t)(row0 + col) * 128 + quad * 8;
  short8 a0 = *(const short8*)(ar);
  short8 a1 = *(const short8*)(ar + 32);
  short8 a2 = *(const short8*)(ar + 64);
  short8 a3 = *(const short8*)(ar + 96);
  f32x4 acc = {0.f, 0.f, 0.f, 0.f};
  acc = __builtin_amdgcn_mfma_f32_16x16x32_bf16(a0, b0, acc, 0, 0, 0);
  acc = __builtin_amdgcn_mfma_f32_16x16x32_bf16(a1, b1, acc, 0, 0, 0);
  acc = __builtin_amdgcn_mfma_f32_16x16x32_bf16(a2, b2, acc, 0, 0, 0);
  acc = __builtin_amdgcn_mfma_f32_16x16x32_bf16(a3, b3, acc, 0, 0, 0);
#pragma unroll
  for (int r = 0; r < 4; ++r) {
    int row = row0 + quad * 4 + r;
    if (row < N) {
      float o = acc[r] + bv;
      if (C) C[(size_t)row * P + cb + col] = o;
      if (Cb) Cb[(size_t)row * 128 + cb + col] = f2bf(o);
    }
  }
}

// ---- CSR build (by col): hist -> 3-phase scan -> fill ----------------------
__global__ void __launch_bounds__(256) k_hist(const int* __restrict__ eidx,
                                              int* __restrict__ cnt, int E) {
  int e = blockIdx.x * 256 + threadIdx.x;
  if (e < E) atomicAdd(&cnt[eidx[E + e]], 1);
}

__global__ void __launch_bounds__(256) k_scanA(const int* __restrict__ cnt,
                                               int* __restrict__ bsum, int N) {
  __shared__ int sums[256];
  int b = blockIdx.x, t = threadIdx.x;
  int base = b * 2048 + t * 8;
  int s = 0;
#pragma unroll
  for (int k = 0; k < 8; ++k) {
    int i = base + k;
    if (i < N) s += cnt[i];
  }
  sums[t] = s;
  __syncthreads();
  for (int d = 128; d > 0; d >>= 1) {
    if (t < d) sums[t] += sums[t + d];
    __syncthreads();
  }
  if (t == 0) bsum[b] = sums[0];
}

__global__ void k_scanB(const int* __restrict__ bsum, int* __restrict__ boff,
                        int nb) {
  if (threadIdx.x == 0) {
    int run = 0;
    for (int b = 0; b < nb; ++b) {
      boff[b] = run;
      run += bsum[b];
    }
  }
}

__global__ void __launch_bounds__(256) k_scanC(const int* __restrict__ cnt,
    const int* __restrict__ boff, int* __restrict__ ptr,
    int* __restrict__ cursor, int N, int nblocks) {
  __shared__ int sums[256];
  int b = blockIdx.x, t = threadIdx.x;
  int base = b * 2048 + t * 8;
  int vals[8];
  int s = 0;
#pragma unroll
  for (int k = 0; k < 8; ++k) {
    int i = base + k;
    int c = (i < N) ? cnt[i] : 0;
    vals[k] = s;
    s += c;
  }
  sums[t] = s;
  __syncthreads();
  for (int d = 1; d < 256; d <<= 1) {
    int v = (t >= d) ? sums[t - d] : 0;
    __syncthreads();
    sums[t] += v;
    __syncthreads();
  }
  int toff = (t == 0) ? 0 : sums[t - 1];
  int bo = boff[b];
#pragma unroll
  for (int k = 0; k < 8; ++k) {
    int i = base + k;
    if (i < N) {
      int p = bo + toff + vals[k];
      ptr[i] = p;
      cursor[i] = p;
    }
  }
  if (b == nblocks - 1 && t == 255) ptr[N] = bo + sums[255];
}

// fill: CSR-slot scatter of (row, col) so downstream kernels read linearly.
__global__ void __launch_bounds__(256) k_fill(const int* __restrict__ eidx,
    int* __restrict__ cursor, int* __restrict__ adjrow,
    int* __restrict__ adjcol, int E) {
  int e = blockIdx.x * 256 + threadIdx.x;
  if (e >= E) return;
  int r = eidx[e], c = eidx[E + e];
  int pos = atomicAdd(&cursor[c], 1);
  adjrow[pos] = r;
  adjcol[pos] = c;
}

// ---- exact expm of antisym 4x4 via so(4) = su(2) + su(2) -------------------
__device__ __forceinline__ void so4_expm(const float* __restrict__ m,
                                         float* __restrict__ F) {
  float v1 = m[1] - m[4], v2 = m[2] - m[8], v3 = m[3] - m[12];
  float w1 = m[11] - m[14], w2 = m[13] - m[7], w3 = m[6] - m[9];
  float p1 = 0.5f * (v1 + w1), p2 = 0.5f * (v2 + w2), p3 = 0.5f * (v3 + w3);
  float q1 = 0.5f * (v1 - w1), q2 = 0.5f * (v2 - w2), q3 = 0.5f * (v3 - w3);
  float tp2 = p1 * p1 + p2 * p2 + p3 * p3;
  float tq2 = q1 * q1 + q2 * q2 + q3 * q3;
  float tp = sqrtf(tp2), tq = sqrtf(tq2);
  float cp = __cosf(tp);
  float sp = (tp > 1e-6f) ? (__sinf(tp) / tp) : (1.f - tp2 * (1.f / 6.f));
  float cq = __cosf(tq);
  float sq = (tq > 1e-6f) ? (__sinf(tq) / tq) : (1.f - tq2 * (1.f / 6.f));
  float a1 = sp * p1, a2 = sp * p2, a3 = sp * p3;
  float b1 = sq * q1, b2 = sq * q2, b3 = sq * q3;
  float Rp[16] = {cp,  a1,  a2,  a3,  -a1, cp,  a3,  -a2,
                  -a2, -a3, cp,  a1,  -a3, a2,  -a1, cp};
  float Rq[16] = {cq,  b1,  b2,  b3,  -b1, cq,  -b3, b2,
                  -b2, b3,  cq,  -b1, -b3, -b2, b1,  cq};
#pragma unroll
  for (int a = 0; a < 4; ++a)
#pragma unroll
    for (int b = 0; b < 4; ++b) {
      float s = 0.f;
#pragma unroll
      for (int c = 0; c < 4; ++c) s = fmaf(Rp[a * 4 + c], Rq[c * 4 + b], s);
      F[a * 4 + b] = s;
    }
}

// Wave = 16 edges (CSR order). h@w2 via MFMA; C -> per-wave LDS patch;
// lanes 0..15: expm + M-products + bf16 interleaved store (64B/edge).
__global__ void __launch_bounds__(256) k_maps_expm(const u16* __restrict__ pqb,
    const u16* __restrict__ W2T, const float* __restrict__ b1,
    const float* __restrict__ b2, const int* __restrict__ adjrow,
    const int* __restrict__ adjcol, u16* __restrict__ MMb, int E) {
  __shared__ float Ms[4 * 16 * 36];  // per-wave 16x36 patch
  int t = threadIdx.x;
  int wv = t >> 6, lane = t & 63;
  int el = lane & 15, quad = lane >> 4;
  int e = blockIdx.x * 64 + wv * 16 + el;
  int es = (e < E) ? e : (E - 1);
  int row = adjrow[es], col = adjcol[es];
  // B-frags: w2^T, wave-invariant. B[n=el][k=quad*8+j].
  short8 bf00 = *(const short8*)(W2T + (size_t)el * 64 + quad * 8);
  short8 bf01 = *(const short8*)(W2T + (size_t)el * 64 + 32 + quad * 8);
  short8 bf10 = *(const short8*)(W2T + (size_t)(16 + el) * 64 + quad * 8);
  short8 bf11 = *(const short8*)(W2T + (size_t)(16 + el) * 64 + 32 + quad * 8);
  f32x4 acc0 = {0.f, 0.f, 0.f, 0.f};
  f32x4 acc1 = {0.f, 0.f, 0.f, 0.f};
#pragma unroll
  for (int c = 0; c < 2; ++c) {
    short8 pv = *(const short8*)(pqb + (size_t)row * 128 + c * 32 + quad * 8);
    short8 qv =
        *(const short8*)(pqb + (size_t)col * 128 + 64 + c * 32 + quad * 8);
    short8 av;
#pragma unroll
    for (int j = 0; j < 8; ++j) {
      float h = bf2f((u16)pv[j]) + bf2f((u16)qv[j]) + b1[c * 32 + quad * 8 + j];
      av[j] = (short)f2bf(fmaxf(h, 0.f));
    }
    if (c == 0) {
      acc0 = __builtin_amdgcn_mfma_f32_16x16x32_bf16(av, bf00, acc0, 0, 0, 0);
      acc1 = __builtin_amdgcn_mfma_f32_16x16x32_bf16(av, bf10, acc1, 0, 0, 0);
    } else {
      acc0 = __builtin_amdgcn_mfma_f32_16x16x32_bf16(av, bf01, acc0, 0, 0, 0);
      acc1 = __builtin_amdgcn_mfma_f32_16x16x32_bf16(av, bf11, acc1, 0, 0, 0);
    }
  }
  // C layout: col(el)=output o, row(quad*4+r)=edge. Transpose via LDS.
  float b2a = b2[el], b2b = b2[16 + el];
  float* ms = Ms + wv * 576;
#pragma unroll
  for (int r = 0; r < 4; ++r) {
    ms[(quad * 4 + r) * 36 + el] = acc0[r] + b2a;
    ms[(quad * 4 + r) * 36 + 16 + el] = acc1[r] + b2b;
  }
  __syncthreads();
  if (lane >= 16 || e >= E) return;
  float m[32];
  const float* mr = Ms + wv * 576 + lane * 36;
#pragma unroll
  for (int i = 0; i < 32; ++i) m[i] = mr[i];
  float Fu[16], Fv[16];
  so4_expm(m, Fu);
  so4_expm(m + 16, Fv);
  u16 ob[32];
#pragma unroll
  for (int a = 0; a < 4; ++a)
#pragma unroll
    for (int b = 0; b < 4; ++b) {
      float s1 = 0.f, s2 = 0.f;
#pragma unroll
      for (int c = 0; c < 4; ++c) {
        s1 = fmaf(Fu[c * 4 + a], Fu[c * 4 + b], s1);  // (Fu^T Fu)[a,b]
        s2 = fmaf(Fu[c * 4 + a], Fv[c * 4 + b], s2);  // (Fu^T Fv)[a,b]
      }
      ob[a * 8 + b] = f2bf(s1);
      ob[a * 8 + 4 + b] = f2bf(s2);
    }
  u16* mp = MMb + (size_t)e * 32;  // sequential (CSR order), 64B/edge
#pragma unroll
  for (int i = 0; i < 4; ++i) *(short8*)(mp + i * 8) = *(short8*)(ob + i * 8);
}

// One wave per node: walk CSR segment (unroll-2). Self-term factored:
// sum_e(M1_e . x_i) = (sum_e M1_e) . x_i. M read bf16 (1x16B/edge/lane),
// x_r gathered bf16 (2x8B). Fused elu epilogue; emits fp32 + bf16.
__global__ void __launch_bounds__(256) k_agg(const float* __restrict__ x,
    const u16* __restrict__ xgb, const u16* __restrict__ MMb,
    const int* __restrict__ ptr, const int* __restrict__ adjrow,
    const float* __restrict__ epsp, float* __restrict__ xout,
    u16* __restrict__ xoutb, int N) {
  int wv = threadIdx.x >> 6, lane = threadIdx.x & 63;
  int v = blockIdx.x * 4 + wv;
  if (v >= N) return;
  int p0 = ptr[v], p1 = ptr[v + 1];
  int a = lane & 3, kb = lane & ~3;
  const float* xv = x + (size_t)v * 128;
  float4 xi1 = *(const float4*)(xv + kb);
  float4 xi2 = *(const float4*)(xv + 64 + kb);
  float hv1 = xv[lane], hv2 = xv[64 + lane];
  float s10 = 0.f, s11 = 0.f, s12 = 0.f, s13 = 0.f;  // sum of M1 row a
  float acc1 = 0.f, acc2 = 0.f;                       // -sum M2.x_r
  int j = p0;
  for (; j + 1 < p1; j += 2) {
    int r0 = adjrow[j], r1 = adjrow[j + 1];
    short8 ma = *(const short8*)(MMb + (size_t)j * 32 + a * 8);
    short8 mb = *(const short8*)(MMb + (size_t)(j + 1) * 32 + a * 8);
    ushort4 ya1 = *(const ushort4*)(xgb + (size_t)r0 * 128 + kb);
    ushort4 ya2 = *(const ushort4*)(xgb + (size_t)r0 * 128 + 64 + kb);
    ushort4 yb1 = *(const ushort4*)(xgb + (size_t)r1 * 128 + kb);
    ushort4 yb2 = *(const ushort4*)(xgb + (size_t)r1 * 128 + 64 + kb);
    s10 += bf2f((u16)ma[0]) + bf2f((u16)mb[0]);
    s11 += bf2f((u16)ma[1]) + bf2f((u16)mb[1]);
    s12 += bf2f((u16)ma[2]) + bf2f((u16)mb[2]);
    s13 += bf2f((u16)ma[3]) + bf2f((u16)mb[3]);
    float a4 = bf2f((u16)ma[4]), a5 = bf2f((u16)ma[5]);
    float a6 = bf2f((u16)ma[6]), a7 = bf2f((u16)ma[7]);
    float b4 = bf2f((u16)mb[4]), b5 = bf2f((u16)mb[5]);
    float b6 = bf2f((u16)mb[6]), b7 = bf2f((u16)mb[7]);
    acc1 -= a4 * bf2f(ya1.x) + a5 * bf2f(ya1.y) + a6 * bf2f(ya1.z) +
            a7 * bf2f(ya1.w);
    acc2 -= a4 * bf2f(ya2.x) + a5 * bf2f(ya2.y) + a6 * bf2f(ya2.z) +
            a7 * bf2f(ya2.w);
    acc1 -= b4 * bf2f(yb1.x) + b5 * bf2f(yb1.y) + b6 * bf2f(yb1.z) +
            b7 * bf2f(yb1.w);
    acc2 -= b4 * bf2f(yb2.x) + b5 * bf2f(yb2.y) + b6 * bf2f(yb2.z) +
            b7 * bf2f(yb2.w);
  }
  if (j < p1) {
    int r0 = adjrow[j];
    short8 ma = *(const short8*)(MMb + (size_t)j * 32 + a * 8);
    ushort4 ya1 = *(const ushort4*)(xgb + (size_t)r0 * 128 + kb);
    ushort4 ya2 = *(const ushort4*)(xgb + (size_t)r0 * 128 + 64 + kb);
    s10 += bf2f((u16)ma[0]);
    s11 += bf2f((u16)ma[1]);
    s12 += bf2f((u16)ma[2]);
    s13 += bf2f((u16)ma[3]);
    float a4 = bf2f((u16)ma[4]), a5 = bf2f((u16)ma[5]);
    float a6 = bf2f((u16)ma[6]), a7 = bf2f((u16)ma[7]);
    acc1 -= a4 * bf2f(ya1.x) + a5 * bf2f(ya1.y) + a6 * bf2f(ya1.z) +
            a7 * bf2f(ya1.w);
    acc2 -= a4 * bf2f(ya2.x) + a5 * bf2f(ya2.y) + a6 * bf2f(ya2.z) +
            a7 * bf2f(ya2.w);
  }
  acc1 += s10 * xi1.x + s11 * xi1.y + s12 * xi1.z + s13 * xi1.w;
  acc2 += s10 * xi2.x + s11 * xi2.y + s12 * xi2.z + s13 * xi2.w;
  float eps = *epsp;
  float r1 = hv1 - eps * acc1;
  float r2 = hv2 - eps * acc2;
  r1 = (r1 > 0.f) ? r1 : expm1f(r1);
  r2 = (r2 > 0.f) ? r2 : expm1f(r2);
  xout[(size_t)v * 128 + lane] = r1;
  xout[(size_t)v * 128 + 64 + lane] = r2;
  xoutb[(size_t)v * 128 + lane] = f2bf(r1);
  xoutb[(size_t)v * 128 + 64 + lane] = f2bf(r2);
}

extern "C" void kernel_launch(void* const* d_in, const int* in_sizes, int n_in,
                              void* d_out, int out_size, void* d_ws,
                              size_t ws_size, hipStream_t stream) {
  const float* x = (const float*)d_in[0];
  const int* eidx = (const int*)d_in[1];
  const float* lin_in_w = (const float*)d_in[2];
  const float* lin_in_b = (const float*)d_in[3];
  const float* c0w1 = (const float*)d_in[4];
  const float* c0b1 = (const float*)d_in[5];
  const float* c0w2 = (const float*)d_in[6];
  const float* c0b2 = (const float*)d_in[7];
  const float* c0eps = (const float*)d_in[8];
  const float* c1w1 = (const float*)d_in[9];
  const float* c1b1 = (const float*)d_in[10];
  const float* c1w2 = (const float*)d_in[11];
  const float* c1b2 = (const float*)d_in[12];
  const float* c1eps = (const float*)d_in[13];
  const float* lout_w = (const float*)d_in[14];
  const float* lout_b = (const float*)d_in[15];
  float* out = (float*)d_out;

  int N = in_sizes[0] / 128;
  int E = in_sizes[1] / 2;
  int Npad = N + 64;

  char* ws = (char*)d_ws;
  size_t szH = (size_t)N * 128 * 4;
  size_t szHb = (size_t)Npad * 128 * 2;
  size_t szM = (size_t)E * 32 * 2;  // bf16 MM
  float* H = (float*)ws;
  float* H2 = (float*)(ws + szH);
  u16* MMb = (u16*)(ws + 2 * szH);
  u16* Xb = (u16*)(ws + 2 * szH + szM);
  u16* Hb = (u16*)(ws + 2 * szH + szM + szHb);
  u16* H2b = (u16*)(ws + 2 * szH + szM + 2 * szHb);
  u16* PQb = (u16*)(ws + 2 * szH + szM + 3 * szHb);
  u16* WTin = (u16*)(ws + 2 * szH + szM + 4 * szHb);
  u16* WT1a = WTin + 16384;
  u16* WT1b = WT1a + 16384;
  u16* WTout = WT1b + 16384;
  u16* W2Ta = WTout + 8192;
  u16* W2Tb = W2Ta + 2048;
  char* ip = (char*)(W2Tb + 2048);
  int* cnt = (int*)ip;                                   // N
  int* ptr = (int*)(ip + 4 * (size_t)(N + 64));          // N+1
  int* cursor = (int*)(ip + 8 * (size_t)(N + 64));       // N
  int* adjrow = (int*)(ip + 12 * (size_t)(N + 64));      // E
  int* adjcol = (int*)(ip + 12 * (size_t)(N + 64) + 4 * (size_t)E);  // E
  int* bsum = adjcol + E;                                // 64
  int* boff = bsum + 64;                                 // 64

  dim3 blk(256);
  int gN = (N + 63) / 64;
  int gE = (E + 255) / 256;
  int nsb = (N + 2047) / 2048;

  // packs (+cnt zero), CSR build
  k_cvt_x<<<(N * 32 + 255) / 256, blk, 0, stream>>>(x, Xb, cnt, N * 32, N);
  k_pack_w<<<240, blk, 0, stream>>>(lin_in_w, c0w1, c1w1, lout_w, c0w2, c1w2,
                                    WTin, WT1a, WT1b, WTout, W2Ta, W2Tb);
  k_hist<<<gE, blk, 0, stream>>>(eidx, cnt, E);
  k_scanA<<<nsb, blk, 0, stream>>>(cnt, bsum, N);
  k_scanB<<<1, dim3(64), 0, stream>>>(bsum, boff, nsb);
  k_scanC<<<nsb, blk, 0, stream>>>(cnt, boff, ptr, cursor, N, nsb);
  k_fill<<<gE, blk, 0, stream>>>(eidx, cursor, adjrow, adjcol, E);

  // h0 = x @ lin_in_w + b   (fp32 H + bf16 Hb)
  k_gemm_mfma<<<dim3(gN, 8), blk, 0, stream>>>(Xb, WTin, lin_in_b, H, Hb, N,
                                               128);

  float* cur = H;
  float* nxt = H2;
  u16* curb = Hb;
  u16* nxtb = H2b;
  for (int layer = 0; layer < 2; ++layer) {
    const u16* wt1 = layer ? WT1b : WT1a;
    const u16* w2t = layer ? W2Tb : W2Ta;
    const float* b1 = layer ? c1b1 : c0b1;
    const float* b2 = layer ? c1b2 : c0b2;
    const float* ep = layer ? c1eps : c0eps;
    k_gemm_mfma<<<dim3(gN, 8), blk, 0, stream>>>(curb, wt1, nullptr, nullptr,
                                                 PQb, N, 128);
    k_maps_expm<<<(E + 63) / 64, blk, 0, stream>>>(PQb, w2t, b1, b2, adjrow,
                                                   adjcol, MMb, E);
    k_agg<<<(N + 3) / 4, blk, 0, stream>>>(cur, curb, MMb, ptr, adjrow, ep,
                                           nxt, nxtb, N);
    float* tf = cur; cur = nxt; nxt = tf;
    u16* tb = curb; curb = nxtb; nxtb = tb;
  }

  // out = h @ lin_out_w + b
  k_gemm_mfma<<<dim3(gN, 4), blk, 0, stream>>>(curb, WTout, lout_b, out,
                                               nullptr, N, 64);
}

// Round 14
// 311.120 us; speedup vs baseline: 1.2254x; 1.0289x over previous
//
#include <hip/hip_runtime.h>
#include <math.h>

// ---------------------------------------------------------------------------
// SheafGNN forward. R14:
//  - k_fill: single int2 scattered store (was 2x4B into arrays E apart) --
//    R13 showed 25.5MB WRITE for a 2.5MB adjacency (10x amplification),
//    VALU 0.19% -> pure scatter-bound. adj[] is now int2 (row,col).
//  - k_scanB folded into k_scanC (<=10 block-sums summed inline per block).
//  - k_cvt_x + k_pack_w merged into k_prep. 14 -> 12 dispatches.
//  - maps/agg read adj as int2; numerics untouched.
// ---------------------------------------------------------------------------

using short8 = __attribute__((ext_vector_type(8))) short;
using f32x4 = __attribute__((ext_vector_type(4))) float;
typedef unsigned short u16;

__device__ __forceinline__ u16 f2bf(float f) {  // RNE fp32->bf16
  unsigned u = __float_as_uint(f);
  unsigned r = (u + 0x7FFFu + ((u >> 16) & 1u)) >> 16;
  return (u16)r;
}
__device__ __forceinline__ float bf2f(u16 v) {
  return __uint_as_float(((unsigned)v) << 16);
}

// ---- fused one-time prep: x->bf16, cnt zero, all weight packs --------------
__global__ void __launch_bounds__(256) k_prep(const float* __restrict__ x,
    u16* __restrict__ Xb, int* __restrict__ cnt, int n4, int N,
    const float* __restrict__ win, const float* __restrict__ w1a,
    const float* __restrict__ w1b, const float* __restrict__ wout,
    const float* __restrict__ w2a, const float* __restrict__ w2b,
    u16* __restrict__ WTin, u16* __restrict__ WT1a, u16* __restrict__ WT1b,
    u16* __restrict__ WTout, u16* __restrict__ W2Ta, u16* __restrict__ W2Tb) {
  int idx = blockIdx.x * 256 + threadIdx.x;
  if (idx < N) cnt[idx] = 0;
  if (idx < n4) {
    float4 v = ((const float4*)x)[idx];
    ushort4 o;
    o.x = f2bf(v.x);
    o.y = f2bf(v.y);
    o.z = f2bf(v.z);
    o.w = f2bf(v.w);
    ((ushort4*)Xb)[idx] = o;
  }
  if (idx < 16384) {
    int o = idx >> 7, i = idx & 127;
    WTin[idx] = f2bf(win[i * 128 + o]);
  } else if (idx < 32768) {
    int j = idx - 16384;
    int o = j >> 7, i = j & 127;
    WT1a[j] = f2bf(o < 64 ? w1a[i * 64 + o] : w1a[(128 + i) * 64 + (o - 64)]);
  } else if (idx < 49152) {
    int j = idx - 32768;
    int o = j >> 7, i = j & 127;
    WT1b[j] = f2bf(o < 64 ? w1b[i * 64 + o] : w1b[(128 + i) * 64 + (o - 64)]);
  } else if (idx < 57344) {
    int j = idx - 49152;
    int o = j >> 7, i = j & 127;  // o < 64
    WTout[j] = f2bf(wout[i * 64 + o]);
  } else if (idx < 59392) {
    int j = idx - 57344;
    int o = j >> 6, k = j & 63;  // W2T[o][k] = w2[k][o]
    W2Ta[j] = f2bf(w2a[k * 32 + o]);
  } else if (idx < 61440) {
    int j = idx - 59392;
    int o = j >> 6, k = j & 63;
    W2Tb[j] = f2bf(w2b[k * 32 + o]);
  }
}

// ---- bf16 MFMA GEMM: wave = one 16x16 tile, K=128 --------------------------
__global__ void __launch_bounds__(256) k_gemm_mfma(const u16* __restrict__ Ab,
    const u16* __restrict__ WT, const float* __restrict__ bias,
    float* __restrict__ C, u16* __restrict__ Cb, int N, int P) {
  int t = threadIdx.x;
  int wv = t >> 6, lane = t & 63;
  int row0 = (blockIdx.x << 6) + (wv << 4);
  int cb = blockIdx.y << 4;
  int col = lane & 15, quad = lane >> 4;
  const u16* wrow = WT + (size_t)(cb + col) * 128 + quad * 8;
  short8 b0 = *(const short8*)(wrow);
  short8 b1 = *(const short8*)(wrow + 32);
  short8 b2 = *(const short8*)(wrow + 64);
  short8 b3 = *(const short8*)(wrow + 96);
  float bv = bias ? bias[cb + col] : 0.f;
  const u16* ar = Ab + (size_t)(row0 + col) * 128 + quad * 8;
  short8 a0 = *(const short8*)(ar);
  short8 a1 = *(const short8*)(ar + 32);
  short8 a2 = *(const short8*)(ar + 64);
  short8 a3 = *(const short8*)(ar + 96);
  f32x4 acc = {0.f, 0.f, 0.f, 0.f};
  acc = __builtin_amdgcn_mfma_f32_16x16x32_bf16(a0, b0, acc, 0, 0, 0);
  acc = __builtin_amdgcn_mfma_f32_16x16x32_bf16(a1, b1, acc, 0, 0, 0);
  acc = __builtin_amdgcn_mfma_f32_16x16x32_bf16(a2, b2, acc, 0, 0, 0);
  acc = __builtin_amdgcn_mfma_f32_16x16x32_bf16(a3, b3, acc, 0, 0, 0);
#pragma unroll
  for (int r = 0; r < 4; ++r) {
    int row = row0 + quad * 4 + r;
    if (row < N) {
      float o = acc[r] + bv;
      if (C) C[(size_t)row * P + cb + col] = o;
      if (Cb) Cb[(size_t)row * 128 + cb + col] = f2bf(o);
    }
  }
}

// ---- CSR build (by col): hist -> 2-phase scan -> fill ----------------------
__global__ void __launch_bounds__(256) k_hist(const int* __restrict__ eidx,
                                              int* __restrict__ cnt, int E) {
  int e = blockIdx.x * 256 + threadIdx.x;
  if (e < E) atomicAdd(&cnt[eidx[E + e]], 1);
}

__global__ void __launch_bounds__(256) k_scanA(const int* __restrict__ cnt,
                                               int* __restrict__ bsum, int N) {
  __shared__ int sums[256];
  int b = blockIdx.x, t = threadIdx.x;
  int base = b * 2048 + t * 8;
  int s = 0;
#pragma unroll
  for (int k = 0; k < 8; ++k) {
    int i = base + k;
    if (i < N) s += cnt[i];
  }
  sums[t] = s;
  __syncthreads();
  for (int d = 128; d > 0; d >>= 1) {
    if (t < d) sums[t] += sums[t + d];
    __syncthreads();
  }
  if (t == 0) bsum[b] = sums[0];
}

__global__ void __launch_bounds__(256) k_scanC(const int* __restrict__ cnt,
    const int* __restrict__ bsum, int* __restrict__ ptr,
    int* __restrict__ cursor, int N, int nblocks) {
  __shared__ int sums[256];
  int b = blockIdx.x, t = threadIdx.x;
  int bo = 0;
  for (int k = 0; k < b; ++k) bo += bsum[k];  // <=10 iterations, s_loads
  int base = b * 2048 + t * 8;
  int vals[8];
  int s = 0;
#pragma unroll
  for (int k = 0; k < 8; ++k) {
    int i = base + k;
    int c = (i < N) ? cnt[i] : 0;
    vals[k] = s;
    s += c;
  }
  sums[t] = s;
  __syncthreads();
  for (int d = 1; d < 256; d <<= 1) {
    int v = (t >= d) ? sums[t - d] : 0;
    __syncthreads();
    sums[t] += v;
    __syncthreads();
  }
  int toff = (t == 0) ? 0 : sums[t - 1];
#pragma unroll
  for (int k = 0; k < 8; ++k) {
    int i = base + k;
    if (i < N) {
      int p = bo + toff + vals[k];
      ptr[i] = p;
      cursor[i] = p;
    }
  }
  if (b == nblocks - 1 && t == 255) ptr[N] = bo + sums[255];
}

// fill: one scattered int2 store per edge (row,col packed).
__global__ void __launch_bounds__(256) k_fill(const int* __restrict__ eidx,
    int* __restrict__ cursor, int2* __restrict__ adj, int E) {
  int e = blockIdx.x * 256 + threadIdx.x;
  if (e >= E) return;
  int r = eidx[e], c = eidx[E + e];
  int pos = atomicAdd(&cursor[c], 1);
  adj[pos] = make_int2(r, c);
}

// ---- exact expm of antisym 4x4 via so(4) = su(2) + su(2) -------------------
__device__ __forceinline__ void so4_expm(const float* __restrict__ m,
                                         float* __restrict__ F) {
  float v1 = m[1] - m[4], v2 = m[2] - m[8], v3 = m[3] - m[12];
  float w1 = m[11] - m[14], w2 = m[13] - m[7], w3 = m[6] - m[9];
  float p1 = 0.5f * (v1 + w1), p2 = 0.5f * (v2 + w2), p3 = 0.5f * (v3 + w3);
  float q1 = 0.5f * (v1 - w1), q2 = 0.5f * (v2 - w2), q3 = 0.5f * (v3 - w3);
  float tp2 = p1 * p1 + p2 * p2 + p3 * p3;
  float tq2 = q1 * q1 + q2 * q2 + q3 * q3;
  float tp = sqrtf(tp2), tq = sqrtf(tq2);
  float cp = __cosf(tp);
  float sp = (tp > 1e-6f) ? (__sinf(tp) / tp) : (1.f - tp2 * (1.f / 6.f));
  float cq = __cosf(tq);
  float sq = (tq > 1e-6f) ? (__sinf(tq) / tq) : (1.f - tq2 * (1.f / 6.f));
  float a1 = sp * p1, a2 = sp * p2, a3 = sp * p3;
  float b1 = sq * q1, b2 = sq * q2, b3 = sq * q3;
  float Rp[16] = {cp,  a1,  a2,  a3,  -a1, cp,  a3,  -a2,
                  -a2, -a3, cp,  a1,  -a3, a2,  -a1, cp};
  float Rq[16] = {cq,  b1,  b2,  b3,  -b1, cq,  -b3, b2,
                  -b2, b3,  cq,  -b1, -b3, -b2, b1,  cq};
#pragma unroll
  for (int a = 0; a < 4; ++a)
#pragma unroll
    for (int b = 0; b < 4; ++b) {
      float s = 0.f;
#pragma unroll
      for (int c = 0; c < 4; ++c) s = fmaf(Rp[a * 4 + c], Rq[c * 4 + b], s);
      F[a * 4 + b] = s;
    }
}

// Wave = 16 edges (CSR order). h@w2 via MFMA; C -> per-wave LDS patch;
// lanes 0..15: expm + M-products + bf16 interleaved store (64B/edge).
__global__ void __launch_bounds__(256) k_maps_expm(const u16* __restrict__ pqb,
    const u16* __restrict__ W2T, const float* __restrict__ b1,
    const float* __restrict__ b2, const int2* __restrict__ adj,
    u16* __restrict__ MMb, int E) {
  __shared__ float Ms[4 * 16 * 36];  // per-wave 16x36 patch
  int t = threadIdx.x;
  int wv = t >> 6, lane = t & 63;
  int el = lane & 15, quad = lane >> 4;
  int e = blockIdx.x * 64 + wv * 16 + el;
  int es = (e < E) ? e : (E - 1);
  int2 rc = adj[es];
  int row = rc.x, col = rc.y;
  // B-frags: w2^T, wave-invariant. B[n=el][k=quad*8+j].
  short8 bf00 = *(const short8*)(W2T + (size_t)el * 64 + quad * 8);
  short8 bf01 = *(const short8*)(W2T + (size_t)el * 64 + 32 + quad * 8);
  short8 bf10 = *(const short8*)(W2T + (size_t)(16 + el) * 64 + quad * 8);
  short8 bf11 = *(const short8*)(W2T + (size_t)(16 + el) * 64 + 32 + quad * 8);
  f32x4 acc0 = {0.f, 0.f, 0.f, 0.f};
  f32x4 acc1 = {0.f, 0.f, 0.f, 0.f};
#pragma unroll
  for (int c = 0; c < 2; ++c) {
    short8 pv = *(const short8*)(pqb + (size_t)row * 128 + c * 32 + quad * 8);
    short8 qv =
        *(const short8*)(pqb + (size_t)col * 128 + 64 + c * 32 + quad * 8);
    short8 av;
#pragma unroll
    for (int j = 0; j < 8; ++j) {
      float h = bf2f((u16)pv[j]) + bf2f((u16)qv[j]) + b1[c * 32 + quad * 8 + j];
      av[j] = (short)f2bf(fmaxf(h, 0.f));
    }
    if (c == 0) {
      acc0 = __builtin_amdgcn_mfma_f32_16x16x32_bf16(av, bf00, acc0, 0, 0, 0);
      acc1 = __builtin_amdgcn_mfma_f32_16x16x32_bf16(av, bf10, acc1, 0, 0, 0);
    } else {
      acc0 = __builtin_amdgcn_mfma_f32_16x16x32_bf16(av, bf01, acc0, 0, 0, 0);
      acc1 = __builtin_amdgcn_mfma_f32_16x16x32_bf16(av, bf11, acc1, 0, 0, 0);
    }
  }
  // C layout: col(el)=output o, row(quad*4+r)=edge. Transpose via LDS.
  float b2a = b2[el], b2b = b2[16 + el];
  float* ms = Ms + wv * 576;
#pragma unroll
  for (int r = 0; r < 4; ++r) {
    ms[(quad * 4 + r) * 36 + el] = acc0[r] + b2a;
    ms[(quad * 4 + r) * 36 + 16 + el] = acc1[r] + b2b;
  }
  __syncthreads();
  if (lane >= 16 || e >= E) return;
  float m[32];
  const float* mr = Ms + wv * 576 + lane * 36;
#pragma unroll
  for (int i = 0; i < 32; ++i) m[i] = mr[i];
  float Fu[16], Fv[16];
  so4_expm(m, Fu);
  so4_expm(m + 16, Fv);
  u16 ob[32];
#pragma unroll
  for (int a = 0; a < 4; ++a)
#pragma unroll
    for (int b = 0; b < 4; ++b) {
      float s1 = 0.f, s2 = 0.f;
#pragma unroll
      for (int c = 0; c < 4; ++c) {
        s1 = fmaf(Fu[c * 4 + a], Fu[c * 4 + b], s1);  // (Fu^T Fu)[a,b]
        s2 = fmaf(Fu[c * 4 + a], Fv[c * 4 + b], s2);  // (Fu^T Fv)[a,b]
      }
      ob[a * 8 + b] = f2bf(s1);
      ob[a * 8 + 4 + b] = f2bf(s2);
    }
  u16* mp = MMb + (size_t)e * 32;  // sequential (CSR order), 64B/edge
#pragma unroll
  for (int i = 0; i < 4; ++i) *(short8*)(mp + i * 8) = *(short8*)(ob + i * 8);
}

// One wave per node: walk CSR segment (unroll-2). Self-term factored:
// sum_e(M1_e . x_i) = (sum_e M1_e) . x_i. M read bf16 (1x16B/edge/lane),
// x_r gathered bf16 (2x8B). Fused elu epilogue; emits fp32 + bf16.
__global__ void __launch_bounds__(256) k_agg(const float* __restrict__ x,
    const u16* __restrict__ xgb, const u16* __restrict__ MMb,
    const int* __restrict__ ptr, const int2* __restrict__ adj,
    const float* __restrict__ epsp, float* __restrict__ xout,
    u16* __restrict__ xoutb, int N) {
  int wv = threadIdx.x >> 6, lane = threadIdx.x & 63;
  int v = blockIdx.x * 4 + wv;
  if (v >= N) return;
  int p0 = ptr[v], p1 = ptr[v + 1];
  int a = lane & 3, kb = lane & ~3;
  const float* xv = x + (size_t)v * 128;
  float4 xi1 = *(const float4*)(xv + kb);
  float4 xi2 = *(const float4*)(xv + 64 + kb);
  float hv1 = xv[lane], hv2 = xv[64 + lane];
  float s10 = 0.f, s11 = 0.f, s12 = 0.f, s13 = 0.f;  // sum of M1 row a
  float acc1 = 0.f, acc2 = 0.f;                       // -sum M2.x_r
  int j = p0;
  for (; j + 1 < p1; j += 2) {
    int r0 = adj[j].x, r1 = adj[j + 1].x;
    short8 ma = *(const short8*)(MMb + (size_t)j * 32 + a * 8);
    short8 mb = *(const short8*)(MMb + (size_t)(j + 1) * 32 + a * 8);
    ushort4 ya1 = *(const ushort4*)(xgb + (size_t)r0 * 128 + kb);
    ushort4 ya2 = *(const ushort4*)(xgb + (size_t)r0 * 128 + 64 + kb);
    ushort4 yb1 = *(const ushort4*)(xgb + (size_t)r1 * 128 + kb);
    ushort4 yb2 = *(const ushort4*)(xgb + (size_t)r1 * 128 + 64 + kb);
    s10 += bf2f((u16)ma[0]) + bf2f((u16)mb[0]);
    s11 += bf2f((u16)ma[1]) + bf2f((u16)mb[1]);
    s12 += bf2f((u16)ma[2]) + bf2f((u16)mb[2]);
    s13 += bf2f((u16)ma[3]) + bf2f((u16)mb[3]);
    float a4 = bf2f((u16)ma[4]), a5 = bf2f((u16)ma[5]);
    float a6 = bf2f((u16)ma[6]), a7 = bf2f((u16)ma[7]);
    float b4 = bf2f((u16)mb[4]), b5 = bf2f((u16)mb[5]);
    float b6 = bf2f((u16)mb[6]), b7 = bf2f((u16)mb[7]);
    acc1 -= a4 * bf2f(ya1.x) + a5 * bf2f(ya1.y) + a6 * bf2f(ya1.z) +
            a7 * bf2f(ya1.w);
    acc2 -= a4 * bf2f(ya2.x) + a5 * bf2f(ya2.y) + a6 * bf2f(ya2.z) +
            a7 * bf2f(ya2.w);
    acc1 -= b4 * bf2f(yb1.x) + b5 * bf2f(yb1.y) + b6 * bf2f(yb1.z) +
            b7 * bf2f(yb1.w);
    acc2 -= b4 * bf2f(yb2.x) + b5 * bf2f(yb2.y) + b6 * bf2f(yb2.z) +
            b7 * bf2f(yb2.w);
  }
  if (j < p1) {
    int r0 = adj[j].x;
    short8 ma = *(const short8*)(MMb + (size_t)j * 32 + a * 8);
    ushort4 ya1 = *(const ushort4*)(xgb + (size_t)r0 * 128 + kb);
    ushort4 ya2 = *(const ushort4*)(xgb + (size_t)r0 * 128 + 64 + kb);
    s10 += bf2f((u16)ma[0]);
    s11 += bf2f((u16)ma[1]);
    s12 += bf2f((u16)ma[2]);
    s13 += bf2f((u16)ma[3]);
    float a4 = bf2f((u16)ma[4]), a5 = bf2f((u16)ma[5]);
    float a6 = bf2f((u16)ma[6]), a7 = bf2f((u16)ma[7]);
    acc1 -= a4 * bf2f(ya1.x) + a5 * bf2f(ya1.y) + a6 * bf2f(ya1.z) +
            a7 * bf2f(ya1.w);
    acc2 -= a4 * bf2f(ya2.x) + a5 * bf2f(ya2.y) + a6 * bf2f(ya2.z) +
            a7 * bf2f(ya2.w);
  }
  acc1 += s10 * xi1.x + s11 * xi1.y + s12 * xi1.z + s13 * xi1.w;
  acc2 += s10 * xi2.x + s11 * xi2.y + s12 * xi2.z + s13 * xi2.w;
  float eps = *epsp;
  float r1 = hv1 - eps * acc1;
  float r2 = hv2 - eps * acc2;
  r1 = (r1 > 0.f) ? r1 : expm1f(r1);
  r2 = (r2 > 0.f) ? r2 : expm1f(r2);
  xout[(size_t)v * 128 + lane] = r1;
  xout[(size_t)v * 128 + 64 + lane] = r2;
  xoutb[(size_t)v * 128 + lane] = f2bf(r1);
  xoutb[(size_t)v * 128 + 64 + lane] = f2bf(r2);
}

extern "C" void kernel_launch(void* const* d_in, const int* in_sizes, int n_in,
                              void* d_out, int out_size, void* d_ws,
                              size_t ws_size, hipStream_t stream) {
  const float* x = (const float*)d_in[0];
  const int* eidx = (const int*)d_in[1];
  const float* lin_in_w = (const float*)d_in[2];
  const float* lin_in_b = (const float*)d_in[3];
  const float* c0w1 = (const float*)d_in[4];
  const float* c0b1 = (const float*)d_in[5];
  const float* c0w2 = (const float*)d_in[6];
  const float* c0b2 = (const float*)d_in[7];
  const float* c0eps = (const float*)d_in[8];
  const float* c1w1 = (const float*)d_in[9];
  const float* c1b1 = (const float*)d_in[10];
  const float* c1w2 = (const float*)d_in[11];
  const float* c1b2 = (const float*)d_in[12];
  const float* c1eps = (const float*)d_in[13];
  const float* lout_w = (const float*)d_in[14];
  const float* lout_b = (const float*)d_in[15];
  float* out = (float*)d_out;

  int N = in_sizes[0] / 128;
  int E = in_sizes[1] / 2;
  int Npad = N + 64;

  char* ws = (char*)d_ws;
  size_t szH = (size_t)N * 128 * 4;
  size_t szHb = (size_t)Npad * 128 * 2;
  size_t szM = (size_t)E * 32 * 2;  // bf16 MM
  float* H = (float*)ws;
  float* H2 = (float*)(ws + szH);
  u16* MMb = (u16*)(ws + 2 * szH);
  u16* Xb = (u16*)(ws + 2 * szH + szM);
  u16* Hb = (u16*)(ws + 2 * szH + szM + szHb);
  u16* H2b = (u16*)(ws + 2 * szH + szM + 2 * szHb);
  u16* PQb = (u16*)(ws + 2 * szH + szM + 3 * szHb);
  u16* WTin = (u16*)(ws + 2 * szH + szM + 4 * szHb);
  u16* WT1a = WTin + 16384;
  u16* WT1b = WT1a + 16384;
  u16* WTout = WT1b + 16384;
  u16* W2Ta = WTout + 8192;
  u16* W2Tb = W2Ta + 2048;
  char* ip = (char*)(W2Tb + 2048);
  int* cnt = (int*)ip;                                   // N
  int* ptr = (int*)(ip + 4 * (size_t)(N + 64));          // N+1
  int* cursor = (int*)(ip + 8 * (size_t)(N + 64));       // N
  int2* adj = (int2*)(ip + 12 * (size_t)(N + 64));       // E int2
  int* bsum = (int*)(ip + 12 * (size_t)(N + 64) + 8 * (size_t)E);  // 64

  dim3 blk(256);
  int gN = (N + 63) / 64;
  int gE = (E + 255) / 256;
  int nsb = (N + 2047) / 2048;

  // fused prep (x->bf16, cnt zero, weight packs), then CSR build
  k_prep<<<(N * 32 + 255) / 256, blk, 0, stream>>>(
      x, Xb, cnt, N * 32, N, lin_in_w, c0w1, c1w1, lout_w, c0w2, c1w2, WTin,
      WT1a, WT1b, WTout, W2Ta, W2Tb);
  k_hist<<<gE, blk, 0, stream>>>(eidx, cnt, E);
  k_scanA<<<nsb, blk, 0, stream>>>(cnt, bsum, N);
  k_scanC<<<nsb, blk, 0, stream>>>(cnt, bsum, ptr, cursor, N, nsb);
  k_fill<<<gE, blk, 0, stream>>>(eidx, cursor, adj, E);

  // h0 = x @ lin_in_w + b   (fp32 H + bf16 Hb)
  k_gemm_mfma<<<dim3(gN, 8), blk, 0, stream>>>(Xb, WTin, lin_in_b, H, Hb, N,
                                               128);

  float* cur = H;
  float* nxt = H2;
  u16* curb = Hb;
  u16* nxtb = H2b;
  for (int layer = 0; layer < 2; ++layer) {
    const u16* wt1 = layer ? WT1b : WT1a;
    const u16* w2t = layer ? W2Tb : W2Ta;
    const float* b1 = layer ? c1b1 : c0b1;
    const float* b2 = layer ? c1b2 : c0b2;
    const float* ep = layer ? c1eps : c0eps;
    k_gemm_mfma<<<dim3(gN, 8), blk, 0, stream>>>(curb, wt1, nullptr, nullptr,
                                                 PQb, N, 128);
    k_maps_expm<<<(E + 63) / 64, blk, 0, stream>>>(PQb, w2t, b1, b2, adj, MMb,
                                                   E);
    k_agg<<<(N + 3) / 4, blk, 0, stream>>>(cur, curb, MMb, ptr, adj, ep, nxt,
                                           nxtb, N);
    float* tf = cur; cur = nxt; nxt = tf;
    u16* tb = curb; curb = nxtb; nxtb = tb;
  }

  // out = h @ lin_out_w + b
  k_gemm_mfma<<<dim3(gN, 4), blk, 0, stream>>>(curb, WTout, lout_b, out,
                                               nullptr, N, 64);
}

// Round 15
// 282.919 us; speedup vs baseline: 1.3476x; 1.0997x over previous
//
#include <hip/hip_runtime.h>
#include <math.h>

// ---------------------------------------------------------------------------
// SheafGNN forward. R15:
//  - k_conv: maps+agg FUSED, one node per single-wave (64-thr) block.
//    Per <=16-edge batch: gather p-rows (q-part is wave-uniform: col==v in
//    CSR order -- hoisted), MFMA h@w2 (R13 frag layout), LDS transpose
//    (stride 44: float4-aligned, 2-way banks), lanes 0..15 so(4)-expm,
//    fp32 M back to LDS, all lanes aggregate from LDS (unroll-2, edge rows
//    via readlane). Eliminates the 20MB MMb buffer (40MB traffic), 2
//    dispatches, M's bf16 rounding, duplicate adj reads. __syncthreads in
//    a 1-wave block = waitcnt only (R11-verified).
//  - b1 folded into pq-GEMM bias (B1p=[0|b1] built in k_prep).
//  - Rest unchanged from R14. 10 dispatches total.
// ---------------------------------------------------------------------------

using short8 = __attribute__((ext_vector_type(8))) short;
using f32x4 = __attribute__((ext_vector_type(4))) float;
typedef unsigned short u16;

__device__ __forceinline__ u16 f2bf(float f) {  // RNE fp32->bf16
  unsigned u = __float_as_uint(f);
  unsigned r = (u + 0x7FFFu + ((u >> 16) & 1u)) >> 16;
  return (u16)r;
}
__device__ __forceinline__ float bf2f(u16 v) {
  return __uint_as_float(((unsigned)v) << 16);
}

// ---- fused one-time prep: x->bf16, cnt zero, weight packs, pq-bias ---------
__global__ void __launch_bounds__(256) k_prep(const float* __restrict__ x,
    u16* __restrict__ Xb, int* __restrict__ cnt, int n4, int N,
    const float* __restrict__ win, const float* __restrict__ w1a,
    const float* __restrict__ w1b, const float* __restrict__ wout,
    const float* __restrict__ w2a, const float* __restrict__ w2b,
    const float* __restrict__ b1a, const float* __restrict__ b1b,
    u16* __restrict__ WTin, u16* __restrict__ WT1a, u16* __restrict__ WT1b,
    u16* __restrict__ WTout, u16* __restrict__ W2Ta, u16* __restrict__ W2Tb,
    float* __restrict__ B1pa, float* __restrict__ B1pb) {
  int idx = blockIdx.x * 256 + threadIdx.x;
  if (idx < N) cnt[idx] = 0;
  if (idx < n4) {
    float4 v = ((const float4*)x)[idx];
    ushort4 o;
    o.x = f2bf(v.x);
    o.y = f2bf(v.y);
    o.z = f2bf(v.z);
    o.w = f2bf(v.w);
    ((ushort4*)Xb)[idx] = o;
  }
  if (idx < 16384) {
    int o = idx >> 7, i = idx & 127;
    WTin[idx] = f2bf(win[i * 128 + o]);
  } else if (idx < 32768) {
    int j = idx - 16384;
    int o = j >> 7, i = j & 127;
    WT1a[j] = f2bf(o < 64 ? w1a[i * 64 + o] : w1a[(128 + i) * 64 + (o - 64)]);
  } else if (idx < 49152) {
    int j = idx - 32768;
    int o = j >> 7, i = j & 127;
    WT1b[j] = f2bf(o < 64 ? w1b[i * 64 + o] : w1b[(128 + i) * 64 + (o - 64)]);
  } else if (idx < 57344) {
    int j = idx - 49152;
    int o = j >> 7, i = j & 127;  // o < 64
    WTout[j] = f2bf(wout[i * 64 + o]);
  } else if (idx < 59392) {
    int j = idx - 57344;
    int o = j >> 6, k = j & 63;  // W2T[o][k] = w2[k][o]
    W2Ta[j] = f2bf(w2a[k * 32 + o]);
  } else if (idx < 61440) {
    int j = idx - 59392;
    int o = j >> 6, k = j & 63;
    W2Tb[j] = f2bf(w2b[k * 32 + o]);
  } else if (idx < 61568) {
    int j = idx - 61440;
    B1pa[j] = (j < 64) ? 0.f : b1a[j - 64];
  } else if (idx < 61696) {
    int j = idx - 61568;
    B1pb[j] = (j < 64) ? 0.f : b1b[j - 64];
  }
}

// ---- bf16 MFMA GEMM: wave = one 16x16 tile, K=128 --------------------------
__global__ void __launch_bounds__(256) k_gemm_mfma(const u16* __restrict__ Ab,
    const u16* __restrict__ WT, const float* __restrict__ bias,
    float* __restrict__ C, u16* __restrict__ Cb, int N, int P) {
  int t = threadIdx.x;
  int wv = t >> 6, lane = t & 63;
  int row0 = (blockIdx.x << 6) + (wv << 4);
  int cb = blockIdx.y << 4;
  int col = lane & 15, quad = lane >> 4;
  const u16* wrow = WT + (size_t)(cb + col) * 128 + quad * 8;
  short8 b0 = *(const short8*)(wrow);
  short8 b1 = *(const short8*)(wrow + 32);
  short8 b2 = *(const short8*)(wrow + 64);
  short8 b3 = *(const short8*)(wrow + 96);
  float bv = bias ? bias[cb + col] : 0.f;
  const u16* ar = Ab + (size_t)(row0 + col) * 128 + quad * 8;
  short8 a0 = *(const short8*)(ar);
  short8 a1 = *(const short8*)(ar + 32);
  short8 a2 = *(const short8*)(ar + 64);
  short8 a3 = *(const short8*)(ar + 96);
  f32x4 acc = {0.f, 0.f, 0.f, 0.f};
  acc = __builtin_amdgcn_mfma_f32_16x16x32_bf16(a0, b0, acc, 0, 0, 0);
  acc = __builtin_amdgcn_mfma_f32_16x16x32_bf16(a1, b1, acc, 0, 0, 0);
  acc = __builtin_amdgcn_mfma_f32_16x16x32_bf16(a2, b2, acc, 0, 0, 0);
  acc = __builtin_amdgcn_mfma_f32_16x16x32_bf16(a3, b3, acc, 0, 0, 0);
#pragma unroll
  for (int r = 0; r < 4; ++r) {
    int row = row0 + quad * 4 + r;
    if (row < N) {
      float o = acc[r] + bv;
      if (C) C[(size_t)row * P + cb + col] = o;
      if (Cb) Cb[(size_t)row * 128 + cb + col] = f2bf(o);
    }
  }
}

// ---- CSR build (by col): hist -> 2-phase scan -> fill ----------------------
__global__ void __launch_bounds__(256) k_hist(const int* __restrict__ eidx,
                                              int* __restrict__ cnt, int E) {
  int e = blockIdx.x * 256 + threadIdx.x;
  if (e < E) atomicAdd(&cnt[eidx[E + e]], 1);
}

__global__ void __launch_bounds__(256) k_scanA(const int* __restrict__ cnt,
                                               int* __restrict__ bsum, int N) {
  __shared__ int sums[256];
  int b = blockIdx.x, t = threadIdx.x;
  int base = b * 2048 + t * 8;
  int s = 0;
#pragma unroll
  for (int k = 0; k < 8; ++k) {
    int i = base + k;
    if (i < N) s += cnt[i];
  }
  sums[t] = s;
  __syncthreads();
  for (int d = 128; d > 0; d >>= 1) {
    if (t < d) sums[t] += sums[t + d];
    __syncthreads();
  }
  if (t == 0) bsum[b] = sums[0];
}

__global__ void __launch_bounds__(256) k_scanC(const int* __restrict__ cnt,
    const int* __restrict__ bsum, int* __restrict__ ptr,
    int* __restrict__ cursor, int N, int nblocks) {
  __shared__ int sums[256];
  int b = blockIdx.x, t = threadIdx.x;
  int bo = 0;
  for (int k = 0; k < b; ++k) bo += bsum[k];  // <=10 iterations
  int base = b * 2048 + t * 8;
  int vals[8];
  int s = 0;
#pragma unroll
  for (int k = 0; k < 8; ++k) {
    int i = base + k;
    int c = (i < N) ? cnt[i] : 0;
    vals[k] = s;
    s += c;
  }
  sums[t] = s;
  __syncthreads();
  for (int d = 1; d < 256; d <<= 1) {
    int v = (t >= d) ? sums[t - d] : 0;
    __syncthreads();
    sums[t] += v;
    __syncthreads();
  }
  int toff = (t == 0) ? 0 : sums[t - 1];
#pragma unroll
  for (int k = 0; k < 8; ++k) {
    int i = base + k;
    if (i < N) {
      int p = bo + toff + vals[k];
      ptr[i] = p;
      cursor[i] = p;
    }
  }
  if (b == nblocks - 1 && t == 255) ptr[N] = bo + sums[255];
}

__global__ void __launch_bounds__(256) k_fill(const int* __restrict__ eidx,
    int* __restrict__ cursor, int2* __restrict__ adj, int E) {
  int e = blockIdx.x * 256 + threadIdx.x;
  if (e >= E) return;
  int r = eidx[e], c = eidx[E + e];
  int pos = atomicAdd(&cursor[c], 1);
  adj[pos] = make_int2(r, c);
}

// ---- exact expm of antisym 4x4 via so(4) = su(2) + su(2) -------------------
__device__ __forceinline__ void so4_expm(const float* __restrict__ m,
                                         float* __restrict__ F) {
  float v1 = m[1] - m[4], v2 = m[2] - m[8], v3 = m[3] - m[12];
  float w1 = m[11] - m[14], w2 = m[13] - m[7], w3 = m[6] - m[9];
  float p1 = 0.5f * (v1 + w1), p2 = 0.5f * (v2 + w2), p3 = 0.5f * (v3 + w3);
  float q1 = 0.5f * (v1 - w1), q2 = 0.5f * (v2 - w2), q3 = 0.5f * (v3 - w3);
  float tp2 = p1 * p1 + p2 * p2 + p3 * p3;
  float tq2 = q1 * q1 + q2 * q2 + q3 * q3;
  float tp = sqrtf(tp2), tq = sqrtf(tq2);
  float cp = __cosf(tp);
  float sp = (tp > 1e-6f) ? (__sinf(tp) / tp) : (1.f - tp2 * (1.f / 6.f));
  float cq = __cosf(tq);
  float sq = (tq > 1e-6f) ? (__sinf(tq) / tq) : (1.f - tq2 * (1.f / 6.f));
  float a1 = sp * p1, a2 = sp * p2, a3 = sp * p3;
  float b1 = sq * q1, b2 = sq * q2, b3 = sq * q3;
  float Rp[16] = {cp,  a1,  a2,  a3,  -a1, cp,  a3,  -a2,
                  -a2, -a3, cp,  a1,  -a3, a2,  -a1, cp};
  float Rq[16] = {cq,  b1,  b2,  b3,  -b1, cq,  -b3, b2,
                  -b2, b3,  cq,  -b1, -b3, -b2, b1,  cq};
#pragma unroll
  for (int a = 0; a < 4; ++a)
#pragma unroll
    for (int b = 0; b < 4; ++b) {
      float s = 0.f;
#pragma unroll
      for (int c = 0; c < 4; ++c) s = fmaf(Rp[a * 4 + c], Rq[c * 4 + b], s);
      F[a * 4 + b] = s;
    }
}

// ---- fused conv: one node per single-wave block ----------------------------
// Per <=16-edge batch: p gathers + uniform q -> A-frag; MFMA h@w2; LDS
// transpose (stride 44); lanes 0..15 expm + M-products (fp32 in LDS);
// aggregate from LDS with factored self-term. Fused elu epilogue.
__global__ void __launch_bounds__(64) k_conv(const float* __restrict__ x,
    const u16* __restrict__ xgb, const u16* __restrict__ pqb,
    const u16* __restrict__ W2T, const float* __restrict__ b2,
    const int* __restrict__ ptr, const int2* __restrict__ adj,
    const float* __restrict__ epsp, float* __restrict__ xout,
    u16* __restrict__ xoutb, int N) {
  __shared__ float ms[16 * 44];
  int lane = threadIdx.x;
  int v = blockIdx.x;
  if (v >= N) return;
  int p0 = ptr[v], p1 = ptr[v + 1];
  int el = lane & 15, quad = lane >> 4;
  int a = lane & 3, kb = lane & ~3;
  // B-frags: w2^T, wave-invariant. B[n][k=quad*8+j].
  short8 bf00 = *(const short8*)(W2T + (size_t)el * 64 + quad * 8);
  short8 bf01 = *(const short8*)(W2T + (size_t)el * 64 + 32 + quad * 8);
  short8 bf10 = *(const short8*)(W2T + (size_t)(16 + el) * 64 + quad * 8);
  short8 bf11 = *(const short8*)(W2T + (size_t)(16 + el) * 64 + 32 + quad * 8);
  float b2a = b2[el], b2b = b2[16 + el];
  // q-part of h: col == v for every edge of this node (CSR order) -> uniform
  short8 qv0 = *(const short8*)(pqb + (size_t)v * 128 + 64 + quad * 8);
  short8 qv1 = *(const short8*)(pqb + (size_t)v * 128 + 96 + quad * 8);
  const float* xv = x + (size_t)v * 128;
  float4 xi1 = *(const float4*)(xv + kb);
  float4 xi2 = *(const float4*)(xv + 64 + kb);
  float hv1 = xv[lane], hv2 = xv[64 + lane];
  float s10 = 0.f, s11 = 0.f, s12 = 0.f, s13 = 0.f;  // sum of M1 row a
  float acc1 = 0.f, acc2 = 0.f;                       // -sum M2.x_r
  for (int b0 = p0; b0 < p1; b0 += 16) {
    int nb = p1 - b0;
    nb = (nb > 16) ? 16 : nb;
    int ee = b0 + ((el < nb) ? el : (nb - 1));
    int row = adj[ee].x;
    f32x4 c0 = {0.f, 0.f, 0.f, 0.f};
    f32x4 c1 = {0.f, 0.f, 0.f, 0.f};
    {  // k-chunk 0 (feats 0..31); b1 pre-folded into q via GEMM bias
      short8 pv = *(const short8*)(pqb + (size_t)row * 128 + quad * 8);
      short8 av;
#pragma unroll
      for (int j = 0; j < 8; ++j) {
        float h = bf2f((u16)pv[j]) + bf2f((u16)qv0[j]);
        av[j] = (short)f2bf(fmaxf(h, 0.f));
      }
      c0 = __builtin_amdgcn_mfma_f32_16x16x32_bf16(av, bf00, c0, 0, 0, 0);
      c1 = __builtin_amdgcn_mfma_f32_16x16x32_bf16(av, bf10, c1, 0, 0, 0);
    }
    {  // k-chunk 1 (feats 32..63)
      short8 pv = *(const short8*)(pqb + (size_t)row * 128 + 32 + quad * 8);
      short8 av;
#pragma unroll
      for (int j = 0; j < 8; ++j) {
        float h = bf2f((u16)pv[j]) + bf2f((u16)qv1[j]);
        av[j] = (short)f2bf(fmaxf(h, 0.f));
      }
      c0 = __builtin_amdgcn_mfma_f32_16x16x32_bf16(av, bf01, c0, 0, 0, 0);
      c1 = __builtin_amdgcn_mfma_f32_16x16x32_bf16(av, bf11, c1, 0, 0, 0);
    }
    // C layout: row(quad*4+r)=edge, col(el)=output. Transpose via LDS.
#pragma unroll
    for (int r = 0; r < 4; ++r) {
      ms[(quad * 4 + r) * 44 + el] = c0[r] + b2a;
      ms[(quad * 4 + r) * 44 + 16 + el] = c1[r] + b2b;
    }
    __syncthreads();  // single-wave block: waitcnt only
    if (lane < 16) {
      float m[32];
      const float* mr = ms + lane * 44;
#pragma unroll
      for (int i = 0; i < 32; ++i) m[i] = mr[i];
      float Fu[16], Fv[16];
      so4_expm(m, Fu);
      so4_expm(m + 16, Fv);
      float* mw = ms + lane * 44;
#pragma unroll
      for (int aa = 0; aa < 4; ++aa)
#pragma unroll
        for (int bb = 0; bb < 4; ++bb) {
          float s1 = 0.f, s2 = 0.f;
#pragma unroll
          for (int cc = 0; cc < 4; ++cc) {
            s1 = fmaf(Fu[cc * 4 + aa], Fu[cc * 4 + bb], s1);  // Fu^T Fu
            s2 = fmaf(Fu[cc * 4 + aa], Fv[cc * 4 + bb], s2);  // Fu^T Fv
          }
          mw[aa * 4 + bb] = s1;
          mw[16 + aa * 4 + bb] = s2;
        }
    }
    __syncthreads();
    int j = 0;
    for (; j + 1 < nb; j += 2) {
      int r0 = __builtin_amdgcn_readlane(row, j);
      int r1 = __builtin_amdgcn_readlane(row, j + 1);
      float4 am1 = *(const float4*)(ms + j * 44 + a * 4);
      float4 am2 = *(const float4*)(ms + j * 44 + 16 + a * 4);
      float4 bm1 = *(const float4*)(ms + (j + 1) * 44 + a * 4);
      float4 bm2 = *(const float4*)(ms + (j + 1) * 44 + 16 + a * 4);
      ushort4 ya1 = *(const ushort4*)(xgb + (size_t)r0 * 128 + kb);
      ushort4 ya2 = *(const ushort4*)(xgb + (size_t)r0 * 128 + 64 + kb);
      ushort4 yb1 = *(const ushort4*)(xgb + (size_t)r1 * 128 + kb);
      ushort4 yb2 = *(const ushort4*)(xgb + (size_t)r1 * 128 + 64 + kb);
      s10 += am1.x + bm1.x;
      s11 += am1.y + bm1.y;
      s12 += am1.z + bm1.z;
      s13 += am1.w + bm1.w;
      acc1 -= am2.x * bf2f(ya1.x) + am2.y * bf2f(ya1.y) +
              am2.z * bf2f(ya1.z) + am2.w * bf2f(ya1.w);
      acc2 -= am2.x * bf2f(ya2.x) + am2.y * bf2f(ya2.y) +
              am2.z * bf2f(ya2.z) + am2.w * bf2f(ya2.w);
      acc1 -= bm2.x * bf2f(yb1.x) + bm2.y * bf2f(yb1.y) +
              bm2.z * bf2f(yb1.z) + bm2.w * bf2f(yb1.w);
      acc2 -= bm2.x * bf2f(yb2.x) + bm2.y * bf2f(yb2.y) +
              bm2.z * bf2f(yb2.z) + bm2.w * bf2f(yb2.w);
    }
    if (j < nb) {
      int r0 = __builtin_amdgcn_readlane(row, j);
      float4 am1 = *(const float4*)(ms + j * 44 + a * 4);
      float4 am2 = *(const float4*)(ms + j * 44 + 16 + a * 4);
      ushort4 ya1 = *(const ushort4*)(xgb + (size_t)r0 * 128 + kb);
      ushort4 ya2 = *(const ushort4*)(xgb + (size_t)r0 * 128 + 64 + kb);
      s10 += am1.x;
      s11 += am1.y;
      s12 += am1.z;
      s13 += am1.w;
      acc1 -= am2.x * bf2f(ya1.x) + am2.y * bf2f(ya1.y) +
              am2.z * bf2f(ya1.z) + am2.w * bf2f(ya1.w);
      acc2 -= am2.x * bf2f(ya2.x) + am2.y * bf2f(ya2.y) +
              am2.z * bf2f(ya2.z) + am2.w * bf2f(ya2.w);
    }
    __syncthreads();  // ms reused next batch
  }
  acc1 += s10 * xi1.x + s11 * xi1.y + s12 * xi1.z + s13 * xi1.w;
  acc2 += s10 * xi2.x + s11 * xi2.y + s12 * xi2.z + s13 * xi2.w;
  float eps = *epsp;
  float r1 = hv1 - eps * acc1;
  float r2 = hv2 - eps * acc2;
  r1 = (r1 > 0.f) ? r1 : expm1f(r1);
  r2 = (r2 > 0.f) ? r2 : expm1f(r2);
  xout[(size_t)v * 128 + lane] = r1;
  xout[(size_t)v * 128 + 64 + lane] = r2;
  xoutb[(size_t)v * 128 + lane] = f2bf(r1);
  xoutb[(size_t)v * 128 + 64 + lane] = f2bf(r2);
}

extern "C" void kernel_launch(void* const* d_in, const int* in_sizes, int n_in,
                              void* d_out, int out_size, void* d_ws,
                              size_t ws_size, hipStream_t stream) {
  const float* x = (const float*)d_in[0];
  const int* eidx = (const int*)d_in[1];
  const float* lin_in_w = (const float*)d_in[2];
  const float* lin_in_b = (const float*)d_in[3];
  const float* c0w1 = (const float*)d_in[4];
  const float* c0b1 = (const float*)d_in[5];
  const float* c0w2 = (const float*)d_in[6];
  const float* c0b2 = (const float*)d_in[7];
  const float* c0eps = (const float*)d_in[8];
  const float* c1w1 = (const float*)d_in[9];
  const float* c1b1 = (const float*)d_in[10];
  const float* c1w2 = (const float*)d_in[11];
  const float* c1b2 = (const float*)d_in[12];
  const float* c1eps = (const float*)d_in[13];
  const float* lout_w = (const float*)d_in[14];
  const float* lout_b = (const float*)d_in[15];
  float* out = (float*)d_out;

  int N = in_sizes[0] / 128;
  int E = in_sizes[1] / 2;
  int Npad = N + 64;

  char* ws = (char*)d_ws;
  size_t szH = (size_t)N * 128 * 4;
  size_t szHb = (size_t)Npad * 128 * 2;
  float* H = (float*)ws;
  float* H2 = (float*)(ws + szH);
  u16* Xb = (u16*)(ws + 2 * szH);
  u16* Hb = (u16*)(ws + 2 * szH + szHb);
  u16* H2b = (u16*)(ws + 2 * szH + 2 * szHb);
  u16* PQb = (u16*)(ws + 2 * szH + 3 * szHb);
  u16* WTin = (u16*)(ws + 2 * szH + 4 * szHb);
  u16* WT1a = WTin + 16384;
  u16* WT1b = WT1a + 16384;
  u16* WTout = WT1b + 16384;
  u16* W2Ta = WTout + 8192;
  u16* W2Tb = W2Ta + 2048;
  float* B1pa = (float*)(W2Tb + 2048);
  float* B1pb = B1pa + 128;
  char* ip = (char*)(B1pb + 128);
  int* cnt = (int*)ip;                                   // N
  int* ptr = (int*)(ip + 4 * (size_t)(N + 64));          // N+1
  int* cursor = (int*)(ip + 8 * (size_t)(N + 64));       // N
  int2* adj = (int2*)(ip + 12 * (size_t)(N + 64));       // E int2
  int* bsum = (int*)(ip + 12 * (size_t)(N + 64) + 8 * (size_t)E);  // 64

  dim3 blk(256);
  int gN = (N + 63) / 64;
  int gE = (E + 255) / 256;
  int nsb = (N + 2047) / 2048;

  // fused prep, CSR build
  k_prep<<<(N * 32 + 255) / 256, blk, 0, stream>>>(
      x, Xb, cnt, N * 32, N, lin_in_w, c0w1, c1w1, lout_w, c0w2, c1w2, c0b1,
      c1b1, WTin, WT1a, WT1b, WTout, W2Ta, W2Tb, B1pa, B1pb);
  k_hist<<<gE, blk, 0, stream>>>(eidx, cnt, E);
  k_scanA<<<nsb, blk, 0, stream>>>(cnt, bsum, N);
  k_scanC<<<nsb, blk, 0, stream>>>(cnt, bsum, ptr, cursor, N, nsb);
  k_fill<<<gE, blk, 0, stream>>>(eidx, cursor, adj, E);

  // h0 = x @ lin_in_w + b   (fp32 H + bf16 Hb)
  k_gemm_mfma<<<dim3(gN, 8), blk, 0, stream>>>(Xb, WTin, lin_in_b, H, Hb, N,
                                               128);

  float* cur = H;
  float* nxt = H2;
  u16* curb = Hb;
  u16* nxtb = H2b;
  for (int layer = 0; layer < 2; ++layer) {
    const u16* wt1 = layer ? WT1b : WT1a;
    const u16* w2t = layer ? W2Tb : W2Ta;
    const float* b1p = layer ? B1pb : B1pa;
    const float* b2 = layer ? c1b2 : c0b2;
    const float* ep = layer ? c1eps : c0eps;
    // pq = h @ W1p + [0|b1]  (bf16 only)
    k_gemm_mfma<<<dim3(gN, 8), blk, 0, stream>>>(curb, wt1, b1p, nullptr, PQb,
                                                 N, 128);
    k_conv<<<N, dim3(64), 0, stream>>>(cur, curb, PQb, w2t, b2, ptr, adj, ep,
                                       nxt, nxtb, N);
    float* tf = cur; cur = nxt; nxt = tf;
    u16* tb = curb; curb = nxtb; nxtb = tb;
  }

  // out = h @ lin_out_w + b
  k_gemm_mfma<<<dim3(gN, 4), blk, 0, stream>>>(curb, WTout, lout_b, out,
                                               nullptr, N, 64);
}